// Round 2
// 3013.965 us; speedup vs baseline: 1.3653x; 1.3653x over previous
//
#include <hip/hip_runtime.h>

// KalmanNet recurrent step, MFMA fp16 rewrite.
//
// Per block: 32 batch rows, full T=32 recurrence. Per step the two big GEMMs
// (GRU gates [32,704]x[704,832], W2 [32,224]x[224,320]) run on
// v_mfma_f32_16x16x32_f16. Weights are pre-packed each launch (prep_kernel)
// into fp16 B-fragment order in __device__ globals (~1.3 MB -> L2-resident).
// Activations are split hi/lo fp16 on the A side (2 MFMAs/tile) so the only
// matmul error is fp16 weight quantization (~2^-12 rms).
//
// Gate column groups (each padded 200->208 = 13 tiles): [z | r | xh | hh].
// xh (cols 416..623) only uses k<480 (a1 rows); hh (624..831) only k in
// [480,704) (h rows) -- the K-loop skips the structurally-zero blocks.
//
// Fragment k-consistency: A and B are packed with the SAME (lanegroup g=l>>4,
// elem i)->k map (k = kt*32 + g*8 + i). Any HW permutation of k within the
// K=32 slice cancels because it applies identically to both operands.
// C/D layout (measured, guide 3): col = lane&15, row = (lane>>4)*4 + reg.
//
// r1: alignas(16) on all vector-accessed LDS arrays (f16x8/f16x4 ds reads
// require 16B/8B alignment; misaligned LDS vector access can fault the GPU).

namespace {

constexpr int T_STEPS = 32;
constexpr int BATCH   = 8192;
constexpr int H1      = 480;   // dense-1 width (a1)
constexpr int HID     = 200;   // GRU hidden
constexpr int H2      = 320;   // dense-2 width (a2)
constexpr int BR      = 32;    // batch rows per block (2 MFMA m-tiles)
constexpr int NTHR    = 512;   // 8 waves
constexpr int KTG     = 22;    // gates K tiles: 704 = 480(a1) + 224(h pad) over 32
constexpr int NTG     = 52;    // gates col tiles: 4 groups * 13 (208 each)
constexpr int NT2     = 20;    // W2 col tiles (320/16)
constexpr int KT2     = 7;     // W2 K tiles (224/32)
constexpr int GSTR    = 34;    // sG row stride in halves (dword stride 17, gcd(17,32)=1)

using f16x8 = __attribute__((ext_vector_type(8))) _Float16;
using f16x4 = __attribute__((ext_vector_type(4))) _Float16;
using f16x2 = __attribute__((ext_vector_type(2))) _Float16;
using f32x4 = __attribute__((ext_vector_type(4))) float;

// packed fp16 weight fragments, rewritten every launch by prep_kernel
__device__ _Float16 g_wcat[NTG * KTG * 512];  // [nt][kt][lane][8]
__device__ _Float16 g_w2[NT2 * KT2 * 512];    // [nt][kt][lane][8]

__device__ __forceinline__ float sigmoid_(float x) { return 1.f / (1.f + __expf(-x)); }
__device__ __forceinline__ float tanh_(float x) {
  x = fminf(fmaxf(x, -15.f), 15.f);
  const float e = __expf(-2.f * x);
  return (1.f - e) / (1.f + e);
}

// element (k, r) -> flat half index in the A-fragment LDS layout
// [kt][m=r>>4][lane = g*16 + (r&15)][i]
__device__ __forceinline__ int afrag_off(int k, int r) {
  const int kt = k >> 5, kk = k & 31;
  return ((kt * 2 + (r >> 4)) * 512) + ((((kk >> 3) << 4) | (r & 15)) * 8) + (kk & 7);
}

// ---------------- weight pre-pack ----------------
__global__ __launch_bounds__(256) void prep_kernel(const float* __restrict__ Wg,
                                                   const float* __restrict__ Ug,
                                                   const float* __restrict__ W2) {
  const int idx = blockIdx.x * 256 + threadIdx.x;
  constexpr int TOT1 = NTG * KTG * 512;
  constexpr int TOT2 = NT2 * KT2 * 512;
  if (idx < TOT1) {
    const int i = idx & 7, l = (idx >> 3) & 63;
    const int nk = idx >> 9;                   // nt*KTG + kt
    const int kt = nk % KTG, nt = nk / KTG;
    const int g = l >> 4, c = l & 15;
    const int k = kt * 32 + g * 8 + i;         // 0..703
    const int grp = nt / 13;                   // 0=z 1=r 2=xh 3=hh
    const int jj = (nt - grp * 13) * 16 + c;   // 0..207
    float wv = 0.f;
    if (jj < HID) {
      if (grp == 0) {
        if (k < H1) wv = Wg[k * 600 + jj];
        else if (k < H1 + HID) wv = Ug[(k - H1) * 600 + jj];
      } else if (grp == 1) {
        if (k < H1) wv = Wg[k * 600 + 200 + jj];
        else if (k < H1 + HID) wv = Ug[(k - H1) * 600 + 200 + jj];
      } else if (grp == 2) {
        if (k < H1) wv = Wg[k * 600 + 400 + jj];            // xh: a1 rows only
      } else {
        if (k >= H1 && k < H1 + HID) wv = Ug[(k - H1) * 600 + 400 + jj];  // hh
      }
    }
    g_wcat[idx] = (_Float16)wv;
  } else if (idx < TOT1 + TOT2) {
    const int id2 = idx - TOT1;
    const int i = id2 & 7, l = (id2 >> 3) & 63;
    const int nk = id2 >> 9;
    const int kt = nk % KT2, nt = nk / KT2;
    const int g = l >> 4, c = l & 15;
    const int k = kt * 32 + g * 8 + i;         // 0..223
    const int col = nt * 16 + c;               // 0..319
    g_w2[id2] = (_Float16)((k < HID) ? W2[k * H2 + col] : 0.f);
  }
}

// ---------------- main recurrent kernel ----------------
__global__ __launch_bounds__(NTHR, 2) void knet_kernel(
    const float* __restrict__ y,    // [T,B,2]
    const float* __restrict__ Fm,   // [4,4]
    const float* __restrict__ Hm,   // [2,4]
    const float* __restrict__ W1,   // [8,480]
    const float* __restrict__ b1,   // [480]
    const float* __restrict__ bg,   // [2,600]
    const float* __restrict__ b2,   // [320]
    const float* __restrict__ W3,   // [320,8]
    const float* __restrict__ b3,   // [8]
    const float* __restrict__ hn0,  // [B,200]
    float* __restrict__ out)        // [T,B,4]
{
  // A-operand fragments of x_cat = [a1(480) | h(200) | 0-pad(24)], hi/lo fp16
  __shared__ alignas(16) _Float16 sAhi[KTG * 2 * 512];   // 45056 B
  __shared__ alignas(16) _Float16 sAlo[KTG * 2 * 512];   // 45056 B
  // gate preacts [832 cols][34]; aliased as a2 [320 cols][34] in phase E/F
  __shared__ alignas(16) _Float16 sG[832 * GSTR];        // 56576 B
  __shared__ alignas(16) float s_in8T[8][BR];            // knet_in transposed
  __shared__ alignas(16) float s_dm1y[BR][2];
  __shared__ alignas(16) float s_prior[BR][4];
  __shared__ alignas(16) float s_post[BR][4];
  __shared__ alignas(16) float s_kg[BR][8];
  __shared__ alignas(16) float s_bias[4][HID];           // combined GRU biases

  const int tid  = threadIdx.x;
  const int lane = tid & 63;
  const int wid  = __builtin_amdgcn_readfirstlane(tid >> 6);  // SGPR -> uniform branches
  const int row0 = blockIdx.x * BR;

  // ---- per-wave tile assignment (interleaved for balance w/ kt-skipping) ----
  int ntv[7], ktbv[7], ktev[7];
#pragma unroll
  for (int it = 0; it < 7; ++it) {
    const int nt = wid + it * 8;
    ntv[it]  = nt;
    ktbv[it] = (nt >= 39) ? 15 : 0;                 // hh: h rows only
    ktev[it] = (nt >= 26 && nt < 39) ? 15 : KTG;    // xh: a1 rows only
  }
  const int nact = (wid < 4) ? 7 : 6;
  int n2v[3];
#pragma unroll
  for (int it = 0; it < 3; ++it) n2v[it] = wid + it * 8;
  const int na2 = (wid < 4) ? 3 : 2;

  // ---- init: biases, hn0 -> h fragments, zero pads & state ----
  if (tid < HID) {
    s_bias[0][tid] = bg[tid]       + bg[600 + tid];   // z (input+recurrent)
    s_bias[1][tid] = bg[200 + tid] + bg[800 + tid];   // r
    s_bias[2][tid] = bg[400 + tid];                   // xh: input bias
    s_bias[3][tid] = bg[1000 + tid];                  // hh: recurrent bias
  }
  for (int e = tid; e < HID * BR; e += NTHR) {
    const int j = e >> 5, r = e & 31;
    const float h0 = hn0[(size_t)(row0 + r) * HID + j];
    const int off = afrag_off(480 + j, r);
    const _Float16 hi = (_Float16)h0;
    sAhi[off] = hi;
    sAlo[off] = (_Float16)(h0 - (float)hi);
  }
  for (int e = tid; e < 24 * BR; e += NTHR) {        // zero rows 680..703
    const int off = afrag_off(680 + (e >> 5), e & 31);
    sAhi[off] = (_Float16)0.f;
    sAlo[off] = (_Float16)0.f;
  }
  if (tid < 128) {
    (&s_prior[0][0])[tid] = 0.f;
    (&s_post[0][0])[tid]  = 0.f;
  }
  __syncthreads();

  for (int t = 0; t < T_STEPS; ++t) {
    // ---- Phase A: prior / innovation / normalized features (32 threads) ----
    if (tid < BR) {
      const int r = tid;
      float post[4], prevpri[4], pri[4];
#pragma unroll
      for (int m = 0; m < 4; ++m) { post[m] = s_post[r][m]; prevpri[m] = s_prior[r][m]; }
#pragma unroll
      for (int m = 0; m < 4; ++m) {
        float s = 0.f;
#pragma unroll
        for (int j = 0; j < 4; ++j) s += Fm[m * 4 + j] * post[j];
        pri[m] = s;
      }
      float s0 = 0.f, s1 = 0.f;
#pragma unroll
      for (int m = 0; m < 4; ++m) { s0 += Hm[m] * pri[m]; s1 += Hm[4 + m] * pri[m]; }
      const size_t yb = ((size_t)t * BATCH + row0 + r) * 2;
      const float dy0 = y[yb] - s0, dy1 = y[yb + 1] - s1;
      float dx[4], ssx = 0.f;
#pragma unroll
      for (int m = 0; m < 4; ++m) { dx[m] = post[m] - prevpri[m]; ssx += dx[m] * dx[m]; }
      const float idx_ = rsqrtf(fmaxf(ssx, 1e-12f));
      const float idy_ = rsqrtf(fmaxf(dy0 * dy0 + dy1 * dy1, 1e-12f));
      const float n0 = dy0 * idy_, n1 = dy1 * idy_;
      s_in8T[0][r] = n0; s_in8T[1][r] = n1; s_in8T[2][r] = n0; s_in8T[3][r] = n1;
#pragma unroll
      for (int m = 0; m < 4; ++m) s_in8T[4 + m][r] = dx[m] * idx_;
      s_dm1y[r][0] = dy0; s_dm1y[r][1] = dy1;
#pragma unroll
      for (int m = 0; m < 4; ++m) s_prior[r][m] = pri[m];
    }
    __syncthreads();

    // ---- Phase B: a1 = relu(in8 @ W1 + b1), write hi/lo A-fragments ----
    {
      const int rB = tid & 31;
      float xv[8];
#pragma unroll
      for (int k = 0; k < 8; ++k) xv[k] = s_in8T[k][rB];
      for (int u = tid; u < 120 * BR; u += NTHR) {   // quads: 120 j-quads x 32 rows
        const int r = u & 31, q = u >> 5;
        const int j0 = q * 4;
        float v0 = b1[j0], v1 = b1[j0 + 1], v2 = b1[j0 + 2], v3 = b1[j0 + 3];
#pragma unroll
        for (int k = 0; k < 8; ++k) {
          const float x = xv[k];
          const float* wp = &W1[k * H1 + j0];
          v0 = fmaf(x, wp[0], v0); v1 = fmaf(x, wp[1], v1);
          v2 = fmaf(x, wp[2], v2); v3 = fmaf(x, wp[3], v3);
        }
        v0 = fmaxf(v0, 0.f); v1 = fmaxf(v1, 0.f);
        v2 = fmaxf(v2, 0.f); v3 = fmaxf(v3, 0.f);
        f16x4 hi, lo;
        hi[0] = (_Float16)v0; lo[0] = (_Float16)(v0 - (float)hi[0]);
        hi[1] = (_Float16)v1; lo[1] = (_Float16)(v1 - (float)hi[1]);
        hi[2] = (_Float16)v2; lo[2] = (_Float16)(v2 - (float)hi[2]);
        hi[3] = (_Float16)v3; lo[3] = (_Float16)(v3 - (float)hi[3]);
        const int off = afrag_off(j0, r);            // j0 % 8 in {0,4}: 8B aligned
        *(f16x4*)&sAhi[off] = hi;
        *(f16x4*)&sAlo[off] = lo;
      }
    }
    __syncthreads();

    // ---- Phase C: gates GEMM on MFMA (all 8 waves) ----
    {
      f32x4 acc[7][2];
#pragma unroll
      for (int it = 0; it < 7; ++it) {
        acc[it][0] = f32x4{0.f, 0.f, 0.f, 0.f};
        acc[it][1] = f32x4{0.f, 0.f, 0.f, 0.f};
      }
      f16x8 bA[7], bB[7], ahA[2], alA[2], ahB[2], alB[2];

#define LDA_G(QT, AH, AL)                                        \
  do {                                                           \
    const int _o = ((QT) * 2) * 512 + lane * 8;                  \
    AH[0] = *(const f16x8*)&sAhi[_o];                            \
    AL[0] = *(const f16x8*)&sAlo[_o];                            \
    AH[1] = *(const f16x8*)&sAhi[_o + 512];                      \
    AL[1] = *(const f16x8*)&sAlo[_o + 512];                      \
  } while (0)

#define LDB_G(QT, BV)                                            \
  do {                                                           \
    _Pragma("unroll")                                            \
    for (int it = 0; it < 7; ++it)                               \
      if (it < nact && (QT) >= ktbv[it] && (QT) < ktev[it])      \
        BV[it] = *(const f16x8*)&g_wcat[(ntv[it] * KTG + (QT)) * 512 + lane * 8]; \
  } while (0)

#define CMP_G(QT, AH, AL, BV)                                    \
  do {                                                           \
    _Pragma("unroll")                                            \
    for (int it = 0; it < 7; ++it)                               \
      if (it < nact && (QT) >= ktbv[it] && (QT) < ktev[it]) {    \
        acc[it][0] = __builtin_amdgcn_mfma_f32_16x16x32_f16(AH[0], BV[it], acc[it][0], 0, 0, 0); \
        acc[it][0] = __builtin_amdgcn_mfma_f32_16x16x32_f16(AL[0], BV[it], acc[it][0], 0, 0, 0); \
        acc[it][1] = __builtin_amdgcn_mfma_f32_16x16x32_f16(AH[1], BV[it], acc[it][1], 0, 0, 0); \
        acc[it][1] = __builtin_amdgcn_mfma_f32_16x16x32_f16(AL[1], BV[it], acc[it][1], 0, 0, 0); \
      }                                                          \
  } while (0)

      LDA_G(0, ahA, alA);
      LDB_G(0, bA);
      for (int kt = 0; kt < KTG; kt += 2) {
        LDA_G(kt + 1, ahB, alB);
        LDB_G(kt + 1, bB);
        CMP_G(kt, ahA, alA, bA);
        if (kt + 2 < KTG) {
          LDA_G(kt + 2, ahA, alA);
          LDB_G(kt + 2, bA);
        }
        CMP_G(kt + 1, ahB, alB, bB);
      }
#undef LDA_G
#undef LDB_G
#undef CMP_G

      // write D tiles -> sG[col][row] (fp16), packed pair stores
      const int lr = lane & 15, lg4 = (lane >> 4) << 2;
#pragma unroll
      for (int it = 0; it < 7; ++it)
        if (it < nact) {
          _Float16* gp = &sG[(ntv[it] * 16 + lr) * GSTR + lg4];
#pragma unroll
          for (int m = 0; m < 2; ++m) {
            f16x2 p0, p1;
            p0[0] = (_Float16)acc[it][m][0]; p0[1] = (_Float16)acc[it][m][1];
            p1[0] = (_Float16)acc[it][m][2]; p1[1] = (_Float16)acc[it][m][3];
            *(f16x2*)(gp + m * 16)     = p0;   // rows m*16+lg4+0,1
            *(f16x2*)(gp + m * 16 + 2) = p1;   // rows m*16+lg4+2,3
          }
        }
    }
    __syncthreads();

    // ---- Phase D: GRU elementwise update; h lives in A-fragments ----
    for (int e = tid; e < HID * BR; e += NTHR) {
      const int j = e >> 5, r = e & 31;
      const float zp = (float)sG[j * GSTR + r]          + s_bias[0][j];
      const float rp = (float)sG[(208 + j) * GSTR + r]  + s_bias[1][j];
      const float xh = (float)sG[(416 + j) * GSTR + r]  + s_bias[2][j];
      const float hh = (float)sG[(624 + j) * GSTR + r]  + s_bias[3][j];
      const int off = afrag_off(480 + j, r);
      const float hold = (float)sAhi[off] + (float)sAlo[off];
      const float z  = sigmoid_(zp);
      const float rr = sigmoid_(rp);
      const float hc = tanh_(xh + rr * hh);
      const float hn = z * hold + (1.f - z) * hc;
      const _Float16 hi = (_Float16)hn;
      sAhi[off] = hi;
      sAlo[off] = (_Float16)(hn - (float)hi);
    }
    __syncthreads();

    // ---- Phase E: a2 = relu(h @ W2 + b2) on MFMA; a2 -> sG (aliased) ----
    {
      f32x4 acc2[3][2];
#pragma unroll
      for (int it = 0; it < 3; ++it) {
        acc2[it][0] = f32x4{0.f, 0.f, 0.f, 0.f};
        acc2[it][1] = f32x4{0.f, 0.f, 0.f, 0.f};
      }
      f16x8 bwA[3], bwB[3], a2hA[2], a2lA[2], a2hB[2], a2lB[2];

#define LDA_2(QT, AH, AL)                                        \
  do {                                                           \
    const int _o = ((15 + (QT)) * 2) * 512 + lane * 8;           \
    AH[0] = *(const f16x8*)&sAhi[_o];                            \
    AL[0] = *(const f16x8*)&sAlo[_o];                            \
    AH[1] = *(const f16x8*)&sAhi[_o + 512];                      \
    AL[1] = *(const f16x8*)&sAlo[_o + 512];                      \
  } while (0)

#define LDB_2(QT, BV)                                            \
  do {                                                           \
    _Pragma("unroll")                                            \
    for (int it = 0; it < 3; ++it)                               \
      if (it < na2)                                              \
        BV[it] = *(const f16x8*)&g_w2[(n2v[it] * KT2 + (QT)) * 512 + lane * 8]; \
  } while (0)

#define CMP_2(QT, AH, AL, BV)                                    \
  do {                                                           \
    _Pragma("unroll")                                            \
    for (int it = 0; it < 3; ++it)                               \
      if (it < na2) {                                            \
        acc2[it][0] = __builtin_amdgcn_mfma_f32_16x16x32_f16(AH[0], BV[it], acc2[it][0], 0, 0, 0); \
        acc2[it][0] = __builtin_amdgcn_mfma_f32_16x16x32_f16(AL[0], BV[it], acc2[it][0], 0, 0, 0); \
        acc2[it][1] = __builtin_amdgcn_mfma_f32_16x16x32_f16(AH[1], BV[it], acc2[it][1], 0, 0, 0); \
        acc2[it][1] = __builtin_amdgcn_mfma_f32_16x16x32_f16(AL[1], BV[it], acc2[it][1], 0, 0, 0); \
      }                                                          \
  } while (0)

      LDA_2(0, a2hA, a2lA);
      LDB_2(0, bwA);
      for (int qt = 0; qt < KT2; qt += 2) {
        if (qt + 1 < KT2) { LDA_2(qt + 1, a2hB, a2lB); LDB_2(qt + 1, bwB); }
        CMP_2(qt, a2hA, a2lA, bwA);
        if (qt + 2 < KT2) { LDA_2(qt + 2, a2hA, a2lA); LDB_2(qt + 2, bwA); }
        if (qt + 1 < KT2) CMP_2(qt + 1, a2hB, a2lB, bwB);
      }
#undef LDA_2
#undef LDB_2
#undef CMP_2

      const int lr = lane & 15, lg4 = (lane >> 4) << 2;
#pragma unroll
      for (int it = 0; it < 3; ++it)
        if (it < na2) {
          const int col = n2v[it] * 16 + lr;
          const float bb = b2[col];
          _Float16* gp = &sG[col * GSTR + lg4];
#pragma unroll
          for (int m = 0; m < 2; ++m) {
            f16x2 p0, p1;
            p0[0] = (_Float16)fmaxf(acc2[it][m][0] + bb, 0.f);
            p0[1] = (_Float16)fmaxf(acc2[it][m][1] + bb, 0.f);
            p1[0] = (_Float16)fmaxf(acc2[it][m][2] + bb, 0.f);
            p1[1] = (_Float16)fmaxf(acc2[it][m][3] + bb, 0.f);
            *(f16x2*)(gp + m * 16)     = p0;
            *(f16x2*)(gp + m * 16 + 2) = p1;
          }
        }
    }
    __syncthreads();

    // ---- Phase F: KG = a2 @ W3 + b3 (256 threads, K=320 fp32 dot) ----
    if (tid < BR * 8) {
      const int r = tid >> 3, c = tid & 7;
      float a = b3[c];
#pragma unroll 8
      for (int k = 0; k < H2; ++k) a = fmaf((float)sG[k * GSTR + r], W3[k * 8 + c], a);
      s_kg[r][c] = a;
    }
    __syncthreads();

    // ---- Phase F2: posterior update + output ----
    if (tid < BR) {
      const int r = tid;
      const float d0 = s_dm1y[r][0], d1 = s_dm1y[r][1];
#pragma unroll
      for (int m = 0; m < 4; ++m) {
        const float p = s_prior[r][m] + s_kg[r][2 * m] * d0 + s_kg[r][2 * m + 1] * d1;
        s_post[r][m] = p;
        out[((size_t)t * BATCH + row0 + r) * 4 + m] = p;
      }
    }
    __syncthreads();
  }
}

}  // namespace

extern "C" void kernel_launch(void* const* d_in, const int* in_sizes, int n_in,
                              void* d_out, int out_size, void* d_ws, size_t ws_size,
                              hipStream_t stream) {
  const float* y   = (const float*)d_in[0];
  const float* Fm  = (const float*)d_in[1];
  const float* Hm  = (const float*)d_in[2];
  const float* W1  = (const float*)d_in[3];
  const float* b1  = (const float*)d_in[4];
  const float* Wg  = (const float*)d_in[5];
  const float* Ug  = (const float*)d_in[6];
  const float* bg  = (const float*)d_in[7];
  const float* W2  = (const float*)d_in[8];
  const float* b2  = (const float*)d_in[9];
  const float* W3  = (const float*)d_in[10];
  const float* b3  = (const float*)d_in[11];
  const float* hn0 = (const float*)d_in[12];
  float* out = (float*)d_out;

  constexpr int PREP_TOT = (NTG * KTG + NT2 * KT2) * 512;
  prep_kernel<<<(PREP_TOT + 255) / 256, 256, 0, stream>>>(Wg, Ug, W2);
  knet_kernel<<<BATCH / BR, NTHR, 0, stream>>>(y, Fm, Hm, W1, b1, bg, b2, W3, b3,
                                               hn0, out);
}

// Round 3
// 2295.680 us; speedup vs baseline: 1.7925x; 1.3129x over previous
//
#include <hip/hip_runtime.h>

// KalmanNet recurrent step, MFMA fp16 rewrite.
//
// Per block: 32 batch rows, full T=32 recurrence. Per step the two big GEMMs
// (GRU gates [32,704]x[704,832], W2 [32,224]x[224,320]) run on
// v_mfma_f32_16x16x32_f16. Weights are pre-packed each launch (prep_kernel)
// into fp16 B-fragment order in __device__ globals (~1.3 MB -> L2-resident).
// Activations are split hi/lo fp16 on the A side (2 MFMAs/tile) so the only
// matmul error is fp16 weight quantization (~2^-12 rms).
//
// Gate column groups (each padded 200->208 = 13 tiles): [z | r | xh | hh].
// xh (cols 416..623) only uses k<480 (a1 rows); hh (624..831) only k in
// [480,704) (h rows) -- the K-loop skips the structurally-zero blocks.
//
// Fragment k-consistency: A and B are packed with the SAME (lanegroup g=l>>4,
// elem i)->k map (k = kt*32 + g*8 + i). Any HW permutation of k within the
// K=32 slice cancels because it applies identically to both operands.
// C/D layout (measured, guide 3): col = lane&15, row = (lane>>4)*4 + reg.
//
// r1: alignas(16) on all vector-accessed LDS arrays.
// r3: (a) amdgpu_waves_per_eu(2,2) -> 256-VGPR budget; round-2 run allocated
//     128 VGPRs against a ~170-reg pipelined live set => spill traffic
//     (WRITE_SIZE 113 MB vs 4 MB of real output). LDS limits us to 1 block
//     (8 waves = 2/SIMD) anyway, so occupancy is unchanged.
//     (b) Phase F (KG = a2 @ W3) moved to MFMA: phase E writes a2 into hi/lo
//     A-fragment slots (dead a1 region), prep packs W3 fragments; kills the
//     K=320 scalar global-load dot loop.

namespace {

constexpr int T_STEPS = 32;
constexpr int BATCH   = 8192;
constexpr int H1      = 480;   // dense-1 width (a1)
constexpr int HID     = 200;   // GRU hidden
constexpr int H2      = 320;   // dense-2 width (a2)
constexpr int BR      = 32;    // batch rows per block (2 MFMA m-tiles)
constexpr int NTHR    = 512;   // 8 waves
constexpr int KTG     = 22;    // gates K tiles: 704 = 480(a1) + 224(h pad) over 32
constexpr int NTG     = 52;    // gates col tiles: 4 groups * 13 (208 each)
constexpr int NT2     = 20;    // W2 col tiles (320/16)
constexpr int KT2     = 7;     // W2 K tiles (224/32)
constexpr int KT3     = 10;    // W3 K tiles (320/32)
constexpr int GSTR    = 34;    // sG row stride in halves (dword stride 17, gcd(17,32)=1)

using f16x8 = __attribute__((ext_vector_type(8))) _Float16;
using f16x4 = __attribute__((ext_vector_type(4))) _Float16;
using f16x2 = __attribute__((ext_vector_type(2))) _Float16;
using f32x4 = __attribute__((ext_vector_type(4))) float;

// packed fp16 weight fragments, rewritten every launch by prep_kernel
__device__ _Float16 g_wcat[NTG * KTG * 512];  // [nt][kt][lane][8]
__device__ _Float16 g_w2[NT2 * KT2 * 512];    // [nt][kt][lane][8]
__device__ _Float16 g_w3[KT3 * 512];          // [kt][lane][8], cols 0..7 = W3, 8..15 = 0

__device__ __forceinline__ float sigmoid_(float x) { return 1.f / (1.f + __expf(-x)); }
__device__ __forceinline__ float tanh_(float x) {
  x = fminf(fmaxf(x, -15.f), 15.f);
  const float e = __expf(-2.f * x);
  return (1.f - e) / (1.f + e);
}

// element (k, r) -> flat half index in the A-fragment LDS layout
// [kt][m=r>>4][lane = g*16 + (r&15)][i]
__device__ __forceinline__ int afrag_off(int k, int r) {
  const int kt = k >> 5, kk = k & 31;
  return ((kt * 2 + (r >> 4)) * 512) + ((((kk >> 3) << 4) | (r & 15)) * 8) + (kk & 7);
}

// ---------------- weight pre-pack ----------------
__global__ __launch_bounds__(256) void prep_kernel(const float* __restrict__ Wg,
                                                   const float* __restrict__ Ug,
                                                   const float* __restrict__ W2,
                                                   const float* __restrict__ W3) {
  const int idx = blockIdx.x * 256 + threadIdx.x;
  constexpr int TOT1 = NTG * KTG * 512;
  constexpr int TOT2 = NT2 * KT2 * 512;
  constexpr int TOT3 = KT3 * 512;
  if (idx < TOT1) {
    const int i = idx & 7, l = (idx >> 3) & 63;
    const int nk = idx >> 9;                   // nt*KTG + kt
    const int kt = nk % KTG, nt = nk / KTG;
    const int g = l >> 4, c = l & 15;
    const int k = kt * 32 + g * 8 + i;         // 0..703
    const int grp = nt / 13;                   // 0=z 1=r 2=xh 3=hh
    const int jj = (nt - grp * 13) * 16 + c;   // 0..207
    float wv = 0.f;
    if (jj < HID) {
      if (grp == 0) {
        if (k < H1) wv = Wg[k * 600 + jj];
        else if (k < H1 + HID) wv = Ug[(k - H1) * 600 + jj];
      } else if (grp == 1) {
        if (k < H1) wv = Wg[k * 600 + 200 + jj];
        else if (k < H1 + HID) wv = Ug[(k - H1) * 600 + 200 + jj];
      } else if (grp == 2) {
        if (k < H1) wv = Wg[k * 600 + 400 + jj];            // xh: a1 rows only
      } else {
        if (k >= H1 && k < H1 + HID) wv = Ug[(k - H1) * 600 + 400 + jj];  // hh
      }
    }
    g_wcat[idx] = (_Float16)wv;
  } else if (idx < TOT1 + TOT2) {
    const int id2 = idx - TOT1;
    const int i = id2 & 7, l = (id2 >> 3) & 63;
    const int nk = id2 >> 9;
    const int kt = nk % KT2, nt = nk / KT2;
    const int g = l >> 4, c = l & 15;
    const int k = kt * 32 + g * 8 + i;         // 0..223
    const int col = nt * 16 + c;               // 0..319
    g_w2[id2] = (_Float16)((k < HID) ? W2[k * H2 + col] : 0.f);
  } else if (idx < TOT1 + TOT2 + TOT3) {
    const int id3 = idx - TOT1 - TOT2;
    const int i = id3 & 7, l = (id3 >> 3) & 63;
    const int kt = id3 >> 9;                   // 0..9
    const int g = l >> 4, c = l & 15;
    const int k = kt * 32 + g * 8 + i;         // 0..319
    g_w3[id3] = (_Float16)((c < 8) ? W3[k * 8 + c] : 0.f);
  }
}

// ---------------- main recurrent kernel ----------------
__global__
__attribute__((amdgpu_flat_work_group_size(NTHR, NTHR)))
__attribute__((amdgpu_waves_per_eu(2, 2)))
void knet_kernel(
    const float* __restrict__ y,    // [T,B,2]
    const float* __restrict__ Fm,   // [4,4]
    const float* __restrict__ Hm,   // [2,4]
    const float* __restrict__ W1,   // [8,480]
    const float* __restrict__ b1,   // [480]
    const float* __restrict__ bg,   // [2,600]
    const float* __restrict__ b2,   // [320]
    const float* __restrict__ b3,   // [8]
    const float* __restrict__ hn0,  // [B,200]
    float* __restrict__ out)        // [T,B,4]
{
  // A-operand fragments: slots 0..14 = a1 rows (k 0..479), 15..21 = h rows
  // (k 480..703). After phase C consumes a1, phase E reuses slots 0..9 for a2
  // fragments (k 0..319) feeding the phase-F MFMA.
  __shared__ alignas(16) _Float16 sAhi[KTG * 2 * 512];   // 45056 B
  __shared__ alignas(16) _Float16 sAlo[KTG * 2 * 512];   // 45056 B
  // gate preacts [832 cols][34] (phase C -> D only)
  __shared__ alignas(16) _Float16 sG[832 * GSTR];        // 56576 B
  __shared__ alignas(16) float s_in8T[8][BR];            // knet_in transposed
  __shared__ alignas(16) float s_dm1y[BR][2];
  __shared__ alignas(16) float s_prior[BR][4];
  __shared__ alignas(16) float s_post[BR][4];
  __shared__ alignas(16) float s_kg[BR][8];
  __shared__ alignas(16) float s_bias[4][HID];           // combined GRU biases

  const int tid  = threadIdx.x;
  const int lane = tid & 63;
  const int wid  = __builtin_amdgcn_readfirstlane(tid >> 6);  // SGPR -> uniform branches
  const int row0 = blockIdx.x * BR;

  // ---- per-wave tile assignment (interleaved for balance w/ kt-skipping) ----
  int ntv[7], ktbv[7], ktev[7];
#pragma unroll
  for (int it = 0; it < 7; ++it) {
    const int nt = wid + it * 8;
    ntv[it]  = nt;
    ktbv[it] = (nt >= 39) ? 15 : 0;                 // hh: h rows only
    ktev[it] = (nt >= 26 && nt < 39) ? 15 : KTG;    // xh: a1 rows only
  }
  const int nact = (wid < 4) ? 7 : 6;
  int n2v[3];
#pragma unroll
  for (int it = 0; it < 3; ++it) n2v[it] = wid + it * 8;
  const int na2 = (wid < 4) ? 3 : 2;

  // ---- init: biases, hn0 -> h fragments, zero pads & state ----
  if (tid < HID) {
    s_bias[0][tid] = bg[tid]       + bg[600 + tid];   // z (input+recurrent)
    s_bias[1][tid] = bg[200 + tid] + bg[800 + tid];   // r
    s_bias[2][tid] = bg[400 + tid];                   // xh: input bias
    s_bias[3][tid] = bg[1000 + tid];                  // hh: recurrent bias
  }
  for (int e = tid; e < HID * BR; e += NTHR) {
    const int j = e >> 5, r = e & 31;
    const float h0 = hn0[(size_t)(row0 + r) * HID + j];
    const int off = afrag_off(480 + j, r);
    const _Float16 hi = (_Float16)h0;
    sAhi[off] = hi;
    sAlo[off] = (_Float16)(h0 - (float)hi);
  }
  for (int e = tid; e < 24 * BR; e += NTHR) {        // zero rows 680..703
    const int off = afrag_off(680 + (e >> 5), e & 31);
    sAhi[off] = (_Float16)0.f;
    sAlo[off] = (_Float16)0.f;
  }
  if (tid < 128) {
    (&s_prior[0][0])[tid] = 0.f;
    (&s_post[0][0])[tid]  = 0.f;
  }
  __syncthreads();

  for (int t = 0; t < T_STEPS; ++t) {
    // ---- Phase A: prior / innovation / normalized features (32 threads) ----
    if (tid < BR) {
      const int r = tid;
      float post[4], prevpri[4], pri[4];
#pragma unroll
      for (int m = 0; m < 4; ++m) { post[m] = s_post[r][m]; prevpri[m] = s_prior[r][m]; }
#pragma unroll
      for (int m = 0; m < 4; ++m) {
        float s = 0.f;
#pragma unroll
        for (int j = 0; j < 4; ++j) s += Fm[m * 4 + j] * post[j];
        pri[m] = s;
      }
      float s0 = 0.f, s1 = 0.f;
#pragma unroll
      for (int m = 0; m < 4; ++m) { s0 += Hm[m] * pri[m]; s1 += Hm[4 + m] * pri[m]; }
      const size_t yb = ((size_t)t * BATCH + row0 + r) * 2;
      const float dy0 = y[yb] - s0, dy1 = y[yb + 1] - s1;
      float dx[4], ssx = 0.f;
#pragma unroll
      for (int m = 0; m < 4; ++m) { dx[m] = post[m] - prevpri[m]; ssx += dx[m] * dx[m]; }
      const float idx_ = rsqrtf(fmaxf(ssx, 1e-12f));
      const float idy_ = rsqrtf(fmaxf(dy0 * dy0 + dy1 * dy1, 1e-12f));
      const float n0 = dy0 * idy_, n1 = dy1 * idy_;
      s_in8T[0][r] = n0; s_in8T[1][r] = n1; s_in8T[2][r] = n0; s_in8T[3][r] = n1;
#pragma unroll
      for (int m = 0; m < 4; ++m) s_in8T[4 + m][r] = dx[m] * idx_;
      s_dm1y[r][0] = dy0; s_dm1y[r][1] = dy1;
#pragma unroll
      for (int m = 0; m < 4; ++m) s_prior[r][m] = pri[m];
    }
    __syncthreads();

    // ---- Phase B: a1 = relu(in8 @ W1 + b1), write hi/lo A-fragments ----
    {
      const int rB = tid & 31;
      float xv[8];
#pragma unroll
      for (int k = 0; k < 8; ++k) xv[k] = s_in8T[k][rB];
      for (int u = tid; u < 120 * BR; u += NTHR) {   // quads: 120 j-quads x 32 rows
        const int r = u & 31, q = u >> 5;
        const int j0 = q * 4;
        float v0 = b1[j0], v1 = b1[j0 + 1], v2 = b1[j0 + 2], v3 = b1[j0 + 3];
#pragma unroll
        for (int k = 0; k < 8; ++k) {
          const float x = xv[k];
          const float* wp = &W1[k * H1 + j0];
          v0 = fmaf(x, wp[0], v0); v1 = fmaf(x, wp[1], v1);
          v2 = fmaf(x, wp[2], v2); v3 = fmaf(x, wp[3], v3);
        }
        v0 = fmaxf(v0, 0.f); v1 = fmaxf(v1, 0.f);
        v2 = fmaxf(v2, 0.f); v3 = fmaxf(v3, 0.f);
        f16x4 hi, lo;
        hi[0] = (_Float16)v0; lo[0] = (_Float16)(v0 - (float)hi[0]);
        hi[1] = (_Float16)v1; lo[1] = (_Float16)(v1 - (float)hi[1]);
        hi[2] = (_Float16)v2; lo[2] = (_Float16)(v2 - (float)hi[2]);
        hi[3] = (_Float16)v3; lo[3] = (_Float16)(v3 - (float)hi[3]);
        const int off = afrag_off(j0, r);            // j0 % 8 in {0,4}: 8B aligned
        *(f16x4*)&sAhi[off] = hi;
        *(f16x4*)&sAlo[off] = lo;
      }
    }
    __syncthreads();

    // ---- Phase C: gates GEMM on MFMA (all 8 waves) ----
    {
      f32x4 acc[7][2];
#pragma unroll
      for (int it = 0; it < 7; ++it) {
        acc[it][0] = f32x4{0.f, 0.f, 0.f, 0.f};
        acc[it][1] = f32x4{0.f, 0.f, 0.f, 0.f};
      }
      f16x8 bA[7], bB[7], ahA[2], alA[2], ahB[2], alB[2];

#define LDA_G(QT, AH, AL)                                        \
  do {                                                           \
    const int _o = ((QT) * 2) * 512 + lane * 8;                  \
    AH[0] = *(const f16x8*)&sAhi[_o];                            \
    AL[0] = *(const f16x8*)&sAlo[_o];                            \
    AH[1] = *(const f16x8*)&sAhi[_o + 512];                      \
    AL[1] = *(const f16x8*)&sAlo[_o + 512];                      \
  } while (0)

#define LDB_G(QT, BV)                                            \
  do {                                                           \
    _Pragma("unroll")                                            \
    for (int it = 0; it < 7; ++it)                               \
      if (it < nact && (QT) >= ktbv[it] && (QT) < ktev[it])      \
        BV[it] = *(const f16x8*)&g_wcat[(ntv[it] * KTG + (QT)) * 512 + lane * 8]; \
  } while (0)

#define CMP_G(QT, AH, AL, BV)                                    \
  do {                                                           \
    _Pragma("unroll")                                            \
    for (int it = 0; it < 7; ++it)                               \
      if (it < nact && (QT) >= ktbv[it] && (QT) < ktev[it]) {    \
        acc[it][0] = __builtin_amdgcn_mfma_f32_16x16x32_f16(AH[0], BV[it], acc[it][0], 0, 0, 0); \
        acc[it][0] = __builtin_amdgcn_mfma_f32_16x16x32_f16(AL[0], BV[it], acc[it][0], 0, 0, 0); \
        acc[it][1] = __builtin_amdgcn_mfma_f32_16x16x32_f16(AH[1], BV[it], acc[it][1], 0, 0, 0); \
        acc[it][1] = __builtin_amdgcn_mfma_f32_16x16x32_f16(AL[1], BV[it], acc[it][1], 0, 0, 0); \
      }                                                          \
  } while (0)

      LDA_G(0, ahA, alA);
      LDB_G(0, bA);
      for (int kt = 0; kt < KTG; kt += 2) {
        LDA_G(kt + 1, ahB, alB);
        LDB_G(kt + 1, bB);
        CMP_G(kt, ahA, alA, bA);
        if (kt + 2 < KTG) {
          LDA_G(kt + 2, ahA, alA);
          LDB_G(kt + 2, bA);
        }
        CMP_G(kt + 1, ahB, alB, bB);
      }
#undef LDA_G
#undef LDB_G
#undef CMP_G

      // write D tiles -> sG[col][row] (fp16), packed pair stores
      const int lr = lane & 15, lg4 = (lane >> 4) << 2;
#pragma unroll
      for (int it = 0; it < 7; ++it)
        if (it < nact) {
          _Float16* gp = &sG[(ntv[it] * 16 + lr) * GSTR + lg4];
#pragma unroll
          for (int m = 0; m < 2; ++m) {
            f16x2 p0, p1;
            p0[0] = (_Float16)acc[it][m][0]; p0[1] = (_Float16)acc[it][m][1];
            p1[0] = (_Float16)acc[it][m][2]; p1[1] = (_Float16)acc[it][m][3];
            *(f16x2*)(gp + m * 16)     = p0;   // rows m*16+lg4+0,1
            *(f16x2*)(gp + m * 16 + 2) = p1;   // rows m*16+lg4+2,3
          }
        }
    }
    __syncthreads();

    // ---- Phase D: GRU elementwise update; h lives in A-fragments ----
    for (int e = tid; e < HID * BR; e += NTHR) {
      const int j = e >> 5, r = e & 31;
      const float zp = (float)sG[j * GSTR + r]          + s_bias[0][j];
      const float rp = (float)sG[(208 + j) * GSTR + r]  + s_bias[1][j];
      const float xh = (float)sG[(416 + j) * GSTR + r]  + s_bias[2][j];
      const float hh = (float)sG[(624 + j) * GSTR + r]  + s_bias[3][j];
      const int off = afrag_off(480 + j, r);
      const float hold = (float)sAhi[off] + (float)sAlo[off];
      const float z  = sigmoid_(zp);
      const float rr = sigmoid_(rp);
      const float hc = tanh_(xh + rr * hh);
      const float hn = z * hold + (1.f - z) * hc;
      const _Float16 hi = (_Float16)hn;
      sAhi[off] = hi;
      sAlo[off] = (_Float16)(hn - (float)hi);
    }
    __syncthreads();

    // ---- Phase E: a2 = relu(h @ W2 + b2) on MFMA; a2 -> A-fragments ----
    {
      f32x4 acc2[3][2];
#pragma unroll
      for (int it = 0; it < 3; ++it) {
        acc2[it][0] = f32x4{0.f, 0.f, 0.f, 0.f};
        acc2[it][1] = f32x4{0.f, 0.f, 0.f, 0.f};
      }
      f16x8 bwA[3], bwB[3], a2hA[2], a2lA[2], a2hB[2], a2lB[2];

#define LDA_2(QT, AH, AL)                                        \
  do {                                                           \
    const int _o = ((15 + (QT)) * 2) * 512 + lane * 8;           \
    AH[0] = *(const f16x8*)&sAhi[_o];                            \
    AL[0] = *(const f16x8*)&sAlo[_o];                            \
    AH[1] = *(const f16x8*)&sAhi[_o + 512];                      \
    AL[1] = *(const f16x8*)&sAlo[_o + 512];                      \
  } while (0)

#define LDB_2(QT, BV)                                            \
  do {                                                           \
    _Pragma("unroll")                                            \
    for (int it = 0; it < 3; ++it)                               \
      if (it < na2)                                              \
        BV[it] = *(const f16x8*)&g_w2[(n2v[it] * KT2 + (QT)) * 512 + lane * 8]; \
  } while (0)

#define CMP_2(QT, AH, AL, BV)                                    \
  do {                                                           \
    _Pragma("unroll")                                            \
    for (int it = 0; it < 3; ++it)                               \
      if (it < na2) {                                            \
        acc2[it][0] = __builtin_amdgcn_mfma_f32_16x16x32_f16(AH[0], BV[it], acc2[it][0], 0, 0, 0); \
        acc2[it][0] = __builtin_amdgcn_mfma_f32_16x16x32_f16(AL[0], BV[it], acc2[it][0], 0, 0, 0); \
        acc2[it][1] = __builtin_amdgcn_mfma_f32_16x16x32_f16(AH[1], BV[it], acc2[it][1], 0, 0, 0); \
        acc2[it][1] = __builtin_amdgcn_mfma_f32_16x16x32_f16(AL[1], BV[it], acc2[it][1], 0, 0, 0); \
      }                                                          \
  } while (0)

      LDA_2(0, a2hA, a2lA);
      LDB_2(0, bwA);
      for (int qt = 0; qt < KT2; qt += 2) {
        if (qt + 1 < KT2) { LDA_2(qt + 1, a2hB, a2lB); LDB_2(qt + 1, bwB); }
        CMP_2(qt, a2hA, a2lA, bwA);
        if (qt + 2 < KT2) { LDA_2(qt + 2, a2hA, a2lA); LDB_2(qt + 2, bwA); }
        if (qt + 1 < KT2) CMP_2(qt + 1, a2hB, a2lB, bwB);
      }
#undef LDA_2
#undef LDB_2
#undef CMP_2

      // store a2 as hi/lo A-fragments into dead a1 slots 0..9 (k = col 0..319)
      const int lr = lane & 15, lg4 = (lane >> 4) << 2;
#pragma unroll
      for (int it = 0; it < 3; ++it)
        if (it < na2) {
          const int col = n2v[it] * 16 + lr;
          const float bb = b2[col];
#pragma unroll
          for (int m = 0; m < 2; ++m) {
#pragma unroll
            for (int reg = 0; reg < 4; ++reg) {
              const float v = fmaxf(acc2[it][m][reg] + bb, 0.f);
              const int off = afrag_off(col, m * 16 + lg4 + reg);
              const _Float16 hi = (_Float16)v;
              sAhi[off] = hi;
              sAlo[off] = (_Float16)(v - (float)hi);
            }
          }
        }
    }
    __syncthreads();

    // ---- Phase F: KG = a2 @ W3 + b3 via MFMA (waves 0,1; m-tile = wid) ----
    if (wid < 2) {
      f32x4 kacc = f32x4{0.f, 0.f, 0.f, 0.f};
#pragma unroll
      for (int kt = 0; kt < KT3; ++kt) {
        const int _o = (kt * 2 + wid) * 512 + lane * 8;
        const f16x8 ah = *(const f16x8*)&sAhi[_o];
        const f16x8 al = *(const f16x8*)&sAlo[_o];
        const f16x8 bw = *(const f16x8*)&g_w3[kt * 512 + lane * 8];
        kacc = __builtin_amdgcn_mfma_f32_16x16x32_f16(ah, bw, kacc, 0, 0, 0);
        kacc = __builtin_amdgcn_mfma_f32_16x16x32_f16(al, bw, kacc, 0, 0, 0);
      }
      const int c = lane & 15;
      if (c < 8) {
        const float bb = b3[c];
        const int rbase = wid * 16 + ((lane >> 4) << 2);
#pragma unroll
        for (int reg = 0; reg < 4; ++reg) s_kg[rbase + reg][c] = kacc[reg] + bb;
      }
    }
    __syncthreads();

    // ---- Phase F2: posterior update + output ----
    if (tid < BR) {
      const int r = tid;
      const float d0 = s_dm1y[r][0], d1 = s_dm1y[r][1];
#pragma unroll
      for (int m = 0; m < 4; ++m) {
        const float p = s_prior[r][m] + s_kg[r][2 * m] * d0 + s_kg[r][2 * m + 1] * d1;
        s_post[r][m] = p;
        out[((size_t)t * BATCH + row0 + r) * 4 + m] = p;
      }
    }
    __syncthreads();
  }
}

}  // namespace

extern "C" void kernel_launch(void* const* d_in, const int* in_sizes, int n_in,
                              void* d_out, int out_size, void* d_ws, size_t ws_size,
                              hipStream_t stream) {
  const float* y   = (const float*)d_in[0];
  const float* Fm  = (const float*)d_in[1];
  const float* Hm  = (const float*)d_in[2];
  const float* W1  = (const float*)d_in[3];
  const float* b1  = (const float*)d_in[4];
  const float* Wg  = (const float*)d_in[5];
  const float* Ug  = (const float*)d_in[6];
  const float* bg  = (const float*)d_in[7];
  const float* W2  = (const float*)d_in[8];
  const float* b2  = (const float*)d_in[9];
  const float* W3  = (const float*)d_in[10];
  const float* b3  = (const float*)d_in[11];
  const float* hn0 = (const float*)d_in[12];
  float* out = (float*)d_out;

  constexpr int PREP_TOT = (NTG * KTG + NT2 * KT2 + KT3) * 512;
  prep_kernel<<<(PREP_TOT + 255) / 256, 256, 0, stream>>>(Wg, Ug, W2, W3);
  knet_kernel<<<BATCH / BR, NTHR, 0, stream>>>(y, Fm, Hm, W1, b1, bg, b2, b3,
                                               hn0, out);
}

// Round 4
// 2019.695 us; speedup vs baseline: 2.0374x; 1.1366x over previous
//
#include <hip/hip_runtime.h>

// KalmanNet recurrent step, MFMA fp16, r4: 16-wave / branch-free / in-register GRU.
//
// Per block: 32 batch rows, full T=32 recurrence, 1024 threads (16 waves,
// 4/SIMD). GEMMs on v_mfma_f32_16x16x32_f16 with A hi/lo fp16 split (exact
// activations; only weight quantization error). Weights prepacked per launch
// into fragment order (g_w1/g_wcat/g_w2/g_w3, ~1.7 MB, L2-resident).
//
// Gates GEMM [32,704]x[704, 4*256pad]: wave w owns j-tile w (cols 16w..16w+15)
// of EACH group {z,r,xh,hh}. Per kt: 3 B loads (z, r, xh-or-hh), 12 MFMAs.
// xh accumulates kt 0..14 (a1 rows, k<480), hh kt 15..21 (h rows) -- the
// boundary is exactly tile-aligned. After the gates GEMM each lane holds
// z,r,xh,hh for (row m*16+(lane>>4)*4+reg, col j=16w+(lane&15)) => GRU update
// entirely in registers; h written back to its A-fragment slots (k=480+j).
//
// Bias folding: phase-B GEMM has a ones-row at k=8 carrying b1; the h-pad
// position k=680 is a permanent 1.0 (gates weights there are zero => inert)
// and g_w2 row k=200 carries b2.
//
// Fragment maps (verified via passing r2/r3): A/B k = kt*32 + (lane>>4)*8 + i,
// A row / B col = lane&15; C/D col = lane&15, row = (lane>>4)*4 + reg.

namespace {

constexpr int T_STEPS = 32;
constexpr int BATCH   = 8192;
constexpr int H1      = 480;
constexpr int HID     = 200;
constexpr int H2      = 320;
constexpr int BR      = 32;    // batch rows per block (2 MFMA m-tiles)
constexpr int NTHR    = 1024;  // 16 waves
constexpr int KTG     = 22;    // gates K tiles (704 = 480 a1 + 224 h/pad)
constexpr int NTG     = 64;    // 4 groups x 16 j-tiles (256-pad each)
constexpr int NTW1    = 32;    // W1 col tiles (512-pad)
constexpr int NT2     = 32;    // W2 col tiles (512-pad, stores guarded <320)
constexpr int KT2     = 7;     // W2 K tiles (224)
constexpr int KT3     = 10;    // W3 K tiles (320)

using f16x8 = __attribute__((ext_vector_type(8))) _Float16;
using f32x4 = __attribute__((ext_vector_type(4))) float;

__device__ _Float16 g_w1[NTW1 * 512];          // [nt][lane][8], k=8 row = b1
__device__ _Float16 g_wcat[NTG * KTG * 512];   // [nt][kt][lane][8]
__device__ _Float16 g_w2[NT2 * KT2 * 512];     // [nt][kt][lane][8], k=200 = b2
__device__ _Float16 g_w3[KT3 * 512];           // [kt][lane][8], cols 8..15 = 0

#define MFMA16(A, B, C) __builtin_amdgcn_mfma_f32_16x16x32_f16((A), (B), (C), 0, 0, 0)

__device__ __forceinline__ float sigmoid_(float x) { return 1.f / (1.f + __expf(-x)); }
__device__ __forceinline__ float tanh_(float x) {
  x = fminf(fmaxf(x, -15.f), 15.f);
  const float e = __expf(-2.f * x);
  return (1.f - e) / (1.f + e);
}
__device__ __forceinline__ f16x8 f16x8_zero() {
  f16x8 v;
#pragma unroll
  for (int i = 0; i < 8; ++i) v[i] = (_Float16)0.f;
  return v;
}

// element (k, r) -> flat half index in A-fragment LDS layout
// [kt][m=r>>4][lane=((k&31)>>3)*16 + (r&15)][i=k&7]
__device__ __forceinline__ int afrag_off(int k, int r) {
  const int kt = k >> 5, kk = k & 31;
  return ((kt * 2 + (r >> 4)) * 512) + ((((kk >> 3) << 4) | (r & 15)) * 8) + (kk & 7);
}

// ---------------- weight pre-pack ----------------
__global__ __launch_bounds__(256) void prep_kernel(
    const float* __restrict__ W1, const float* __restrict__ b1,
    const float* __restrict__ Wg, const float* __restrict__ Ug,
    const float* __restrict__ W2, const float* __restrict__ b2,
    const float* __restrict__ W3) {
  const int idx = blockIdx.x * 256 + threadIdx.x;
  constexpr int TOTW1 = NTW1 * 512;
  constexpr int TOT1  = NTG * KTG * 512;
  constexpr int TOT2  = NT2 * KT2 * 512;
  constexpr int TOT3  = KT3 * 512;
  if (idx < TOTW1) {
    const int i = idx & 7, l = (idx >> 3) & 63, nt = idx >> 9;
    const int g = l >> 4, c = l & 15;
    const int k = g * 8 + i, col = nt * 16 + c;
    float wv = 0.f;
    if (col < H1) {
      if (k < 8) wv = W1[k * H1 + col];
      else if (k == 8) wv = b1[col];
    }
    g_w1[idx] = (_Float16)wv;
  } else if (idx < TOTW1 + TOT1) {
    const int id = idx - TOTW1;
    const int i = id & 7, l = (id >> 3) & 63, nk = id >> 9;
    const int kt = nk % KTG, nt = nk / KTG;
    const int g = l >> 4, c = l & 15;
    const int k = kt * 32 + g * 8 + i;        // 0..703
    const int grp = nt >> 4;                  // 0=z 1=r 2=xh 3=hh
    const int jj = (nt & 15) * 16 + c;        // 0..255
    float wv = 0.f;
    if (jj < HID) {
      if (grp == 0) {
        if (k < H1) wv = Wg[k * 600 + jj];
        else if (k < H1 + HID) wv = Ug[(k - H1) * 600 + jj];
      } else if (grp == 1) {
        if (k < H1) wv = Wg[k * 600 + 200 + jj];
        else if (k < H1 + HID) wv = Ug[(k - H1) * 600 + 200 + jj];
      } else if (grp == 2) {
        if (k < H1) wv = Wg[k * 600 + 400 + jj];           // xh: a1 rows only
      } else {
        if (k >= H1 && k < H1 + HID) wv = Ug[(k - H1) * 600 + 400 + jj];  // hh
      }
    }
    g_wcat[id] = (_Float16)wv;
  } else if (idx < TOTW1 + TOT1 + TOT2) {
    const int id = idx - TOTW1 - TOT1;
    const int i = id & 7, l = (id >> 3) & 63, nk = id >> 9;
    const int kt = nk % KT2, nt = nk / KT2;
    const int g = l >> 4, c = l & 15;
    const int k = kt * 32 + g * 8 + i;        // 0..223
    const int col = nt * 16 + c;
    float wv = 0.f;
    if (col < H2) {
      if (k < HID) wv = W2[k * H2 + col];
      else if (k == 200) wv = b2[col];        // ones-row at k_h=200 (k=680)
    }
    g_w2[id] = (_Float16)wv;
  } else if (idx < TOTW1 + TOT1 + TOT2 + TOT3) {
    const int id = idx - TOTW1 - TOT1 - TOT2;
    const int i = id & 7, l = (id >> 3) & 63, kt = id >> 9;
    const int g = l >> 4, c = l & 15;
    const int k = kt * 32 + g * 8 + i;        // 0..319
    g_w3[id] = (_Float16)((c < 8) ? W3[k * 8 + c] : 0.f);
  }
}

// ---------------- main recurrent kernel ----------------
__global__ __launch_bounds__(NTHR, 4) void knet_kernel(
    const float* __restrict__ y,    // [T,B,2]
    const float* __restrict__ Fm,   // [4,4]
    const float* __restrict__ Hm,   // [2,4]
    const float* __restrict__ bg,   // [2,600]
    const float* __restrict__ b3,   // [8]
    const float* __restrict__ hn0,  // [B,200]
    float* __restrict__ out)        // [T,B,4]
{
  // A-fragments of x_cat = [a1(480) | h(200) | 1.0 @680 | 0-pad]; a2 reuses
  // slots 0..9 between phase E and phase F.
  __shared__ alignas(16) _Float16 sAhi[KTG * 2 * 512];   // 45056 B
  __shared__ alignas(16) _Float16 sAlo[KTG * 2 * 512];   // 45056 B
  __shared__ alignas(16) float s_in8T[8][BR];
  __shared__ alignas(16) float s_kgp[2][BR][8];          // KG k-half partials
  __shared__ alignas(16) float s_bias[4][HID];
  __shared__ alignas(16) float s_fh[32];                 // Fm[16], Hm[8]
  __shared__ alignas(16) float s_b3[8];

  const int tid  = threadIdx.x;
  const int lane = tid & 63;
  const int wid  = __builtin_amdgcn_readfirstlane(tid >> 6);  // 0..15
  const int row0 = blockIdx.x * BR;
  const int rl   = lane & 31;
  const int g4   = (lane >> 4) << 2;

  // ---- init ----
  if (tid < HID) {
    s_bias[0][tid] = bg[tid]       + bg[600 + tid];   // z
    s_bias[1][tid] = bg[200 + tid] + bg[800 + tid];   // r
    s_bias[2][tid] = bg[400 + tid];                   // xh (input bias)
    s_bias[3][tid] = bg[1000 + tid];                  // hh (recurrent bias)
  }
  if (tid < 16) s_fh[tid] = Fm[tid];
  else if (tid < 24) s_fh[tid] = Hm[tid - 16];
  if (tid < 8) s_b3[tid] = b3[tid];
  for (int e = tid; e < HID * BR; e += NTHR) {
    const int j = e >> 5, r = e & 31;
    const float h0 = hn0[(size_t)(row0 + r) * HID + j];
    const int off = afrag_off(480 + j, r);
    const _Float16 hi = (_Float16)h0;
    sAhi[off] = hi;
    sAlo[off] = (_Float16)(h0 - (float)hi);
  }
  for (int e = tid; e < 24 * BR; e += NTHR) {   // k 680..703: 1.0 then zeros
    const int k = 680 + (e >> 5), r = e & 31;
    const int off = afrag_off(k, r);
    sAhi[off] = (_Float16)((k == 680) ? 1.f : 0.f);
    sAlo[off] = (_Float16)0.f;
  }
  __syncthreads();

  // persistent per-lane state (row rl)
  float prior[4] = {0.f, 0.f, 0.f, 0.f};
  float post[4]  = {0.f, 0.f, 0.f, 0.f};
  float d0 = 0.f, d1 = 0.f;

  for (int t = 0; t < T_STEPS; ++t) {
    // ================= phase 1: F2(t-1) + A(t) + W1-GEMM(t) =================
    if (t > 0) {
      float kg[8];
#pragma unroll
      for (int cc = 0; cc < 8; ++cc)
        kg[cc] = s_kgp[0][rl][cc] + s_kgp[1][rl][cc] + s_b3[cc];
#pragma unroll
      for (int m = 0; m < 4; ++m)
        post[m] = prior[m] + kg[2 * m] * d0 + kg[2 * m + 1] * d1;
      if (wid == 0 && lane < 32) {
        float4 o; o.x = post[0]; o.y = post[1]; o.z = post[2]; o.w = post[3];
        *(float4*)&out[((size_t)(t - 1) * BATCH + row0 + rl) * 4] = o;
      }
    }
    {   // ---- A: prior / innovation / features (redundant per wave) ----
      float opri[4], np[4];
#pragma unroll
      for (int m = 0; m < 4; ++m) opri[m] = prior[m];
#pragma unroll
      for (int m = 0; m < 4; ++m) {
        float s = 0.f;
#pragma unroll
        for (int j = 0; j < 4; ++j) s += s_fh[m * 4 + j] * post[j];
        np[m] = s;
      }
      float m0 = 0.f, m1 = 0.f;
#pragma unroll
      for (int m = 0; m < 4; ++m) { m0 += s_fh[16 + m] * np[m]; m1 += s_fh[20 + m] * np[m]; }
      const float2 yv = *(const float2*)&y[((size_t)t * BATCH + row0 + rl) * 2];
      d0 = yv.x - m0;
      d1 = yv.y - m1;
      float dx[4], ssx = 0.f;
#pragma unroll
      for (int m = 0; m < 4; ++m) { dx[m] = post[m] - opri[m]; ssx += dx[m] * dx[m]; }
      const float idx_ = rsqrtf(fmaxf(ssx, 1e-12f));
      const float idy_ = rsqrtf(fmaxf(d0 * d0 + d1 * d1, 1e-12f));
#pragma unroll
      for (int m = 0; m < 4; ++m) prior[m] = np[m];
      if (lane < 32) {
        const float n0 = d0 * idy_, n1 = d1 * idy_;
        s_in8T[0][rl] = n0; s_in8T[1][rl] = n1;
        s_in8T[2][rl] = n0; s_in8T[3][rl] = n1;
#pragma unroll
        for (int m = 0; m < 4; ++m) s_in8T[4 + m][rl] = dx[m] * idx_;
      }
    }
    {   // ---- W1-GEMM: a1 = relu([in8,1] @ [W1;b1]), 2 tiles/wave ----
      f16x8 ah0 = f16x8_zero(), al0 = f16x8_zero();
      f16x8 ah1 = f16x8_zero(), al1 = f16x8_zero();
      const int g = lane >> 4, c = lane & 15;
      if (g == 0) {
#pragma unroll
        for (int i = 0; i < 8; ++i) {
          const float v0 = s_in8T[i][c];
          const float v1 = s_in8T[i][c + 16];
          const _Float16 h0 = (_Float16)v0; ah0[i] = h0; al0[i] = (_Float16)(v0 - (float)h0);
          const _Float16 h1 = (_Float16)v1; ah1[i] = h1; al1[i] = (_Float16)(v1 - (float)h1);
        }
      } else if (g == 1) {
        ah0[0] = (_Float16)1.f;   // ones-row k=8 -> b1
        ah1[0] = (_Float16)1.f;
      }
      f32x4 p00 = {0.f, 0.f, 0.f, 0.f}, p01 = p00, p10 = p00, p11 = p00;
      const f16x8 w1a = *(const f16x8*)&g_w1[(size_t)wid * 512 + lane * 8];
      const f16x8 w1b = *(const f16x8*)&g_w1[(size_t)(16 + wid) * 512 + lane * 8];
      p00 = MFMA16(ah0, w1a, p00); p00 = MFMA16(al0, w1a, p00);
      p01 = MFMA16(ah1, w1a, p01); p01 = MFMA16(al1, w1a, p01);
      p10 = MFMA16(ah0, w1b, p10); p10 = MFMA16(al0, w1b, p10);
      p11 = MFMA16(ah1, w1b, p11); p11 = MFMA16(al1, w1b, p11);
#define ASTORE(A0, A1, COLBASE)                                      \
      { const int col = (COLBASE) + (lane & 15);                     \
        _Pragma("unroll")                                            \
        for (int reg = 0; reg < 4; ++reg) {                          \
          const float v0 = fmaxf(A0[reg], 0.f);                      \
          const float v1 = fmaxf(A1[reg], 0.f);                      \
          const int o0 = afrag_off(col, g4 + reg);                   \
          const int o1 = afrag_off(col, 16 + g4 + reg);              \
          const _Float16 q0 = (_Float16)v0, q1 = (_Float16)v1;       \
          sAhi[o0] = q0; sAlo[o0] = (_Float16)(v0 - (float)q0);      \
          sAhi[o1] = q1; sAlo[o1] = (_Float16)(v1 - (float)q1);      \
        } }
      ASTORE(p00, p01, wid * 16)
      if (wid < 14) ASTORE(p10, p11, (16 + wid) * 16)
    }
    __syncthreads();

    // ================= phase C: gates GEMM (branch-free) =================
    f32x4 aZ0 = {0.f, 0.f, 0.f, 0.f}, aZ1 = aZ0, aR0 = aZ0, aR1 = aZ0;
    f32x4 aX0 = aZ0, aX1 = aZ0, aH0 = aZ0, aH1 = aZ0;
    {
      const _Float16* bzp = g_wcat + ((size_t)(0  + wid) * KTG) * 512 + lane * 8;
      const _Float16* brp = g_wcat + ((size_t)(16 + wid) * KTG) * 512 + lane * 8;
      const _Float16* bxp = g_wcat + ((size_t)(32 + wid) * KTG) * 512 + lane * 8;
      const _Float16* bhp = g_wcat + ((size_t)(48 + wid) * KTG) * 512 + lane * 8;
#pragma unroll
      for (int kt = 0; kt < KTG; ++kt) {
        const f16x8 bz  = *(const f16x8*)(bzp + kt * 512);
        const f16x8 brv = *(const f16x8*)(brp + kt * 512);
        const f16x8 b3v = (kt < 15) ? *(const f16x8*)(bxp + kt * 512)
                                    : *(const f16x8*)(bhp + kt * 512);
        const int _o = kt * 1024 + lane * 8;
        const f16x8 ah0 = *(const f16x8*)&sAhi[_o];
        const f16x8 al0 = *(const f16x8*)&sAlo[_o];
        const f16x8 ah1 = *(const f16x8*)&sAhi[_o + 512];
        const f16x8 al1 = *(const f16x8*)&sAlo[_o + 512];
        aZ0 = MFMA16(ah0, bz, aZ0);  aZ0 = MFMA16(al0, bz, aZ0);
        aZ1 = MFMA16(ah1, bz, aZ1);  aZ1 = MFMA16(al1, bz, aZ1);
        aR0 = MFMA16(ah0, brv, aR0); aR0 = MFMA16(al0, brv, aR0);
        aR1 = MFMA16(ah1, brv, aR1); aR1 = MFMA16(al1, brv, aR1);
        if (kt < 15) {
          aX0 = MFMA16(ah0, b3v, aX0); aX0 = MFMA16(al0, b3v, aX0);
          aX1 = MFMA16(ah1, b3v, aX1); aX1 = MFMA16(al1, b3v, aX1);
        } else {
          aH0 = MFMA16(ah0, b3v, aH0); aH0 = MFMA16(al0, b3v, aH0);
          aH1 = MFMA16(ah1, b3v, aH1); aH1 = MFMA16(al1, b3v, aH1);
        }
      }
    }
    __syncthreads();   // all h reads done before in-place h update

    // ================= phase D': in-register GRU update =================
    if (wid < 13) {
      const int c = lane & 15;
      const int j = wid * 16 + c;
      if (j < HID) {
        const float bz  = s_bias[0][j], brb = s_bias[1][j];
        const float bxh = s_bias[2][j], bhh = s_bias[3][j];
#define GRU1(AZ, AR, AX, AH, MB)                                         \
        _Pragma("unroll")                                                \
        for (int reg = 0; reg < 4; ++reg) {                              \
          const int r = (MB) * 16 + g4 + reg;                            \
          const int off = afrag_off(480 + j, r);                         \
          const float hold = (float)sAhi[off] + (float)sAlo[off];        \
          const float z  = sigmoid_(AZ[reg] + bz);                       \
          const float rr = sigmoid_(AR[reg] + brb);                      \
          const float hc = tanh_((AX[reg] + bxh) + rr * (AH[reg] + bhh));\
          const float hn = z * hold + (1.f - z) * hc;                    \
          const _Float16 qh = (_Float16)hn;                              \
          sAhi[off] = qh;                                                \
          sAlo[off] = (_Float16)(hn - (float)qh);                        \
        }
        GRU1(aZ0, aR0, aX0, aH0, 0)
        GRU1(aZ1, aR1, aX1, aH1, 1)
#undef GRU1
      }
    }
    __syncthreads();

    // ================= phase E: a2 = relu(h @ W2 + b2) =================
    {
      f32x4 e00 = {0.f, 0.f, 0.f, 0.f}, e01 = e00, e10 = e00, e11 = e00;
      const _Float16* w2a = g_w2 + ((size_t)wid * KT2) * 512 + lane * 8;
      const _Float16* w2b = g_w2 + ((size_t)(16 + wid) * KT2) * 512 + lane * 8;
#pragma unroll
      for (int qt = 0; qt < KT2; ++qt) {
        const f16x8 ba = *(const f16x8*)(w2a + qt * 512);
        const f16x8 bb = *(const f16x8*)(w2b + qt * 512);
        const int _o = (15 + qt) * 1024 + lane * 8;
        const f16x8 ah0 = *(const f16x8*)&sAhi[_o];
        const f16x8 al0 = *(const f16x8*)&sAlo[_o];
        const f16x8 ah1 = *(const f16x8*)&sAhi[_o + 512];
        const f16x8 al1 = *(const f16x8*)&sAlo[_o + 512];
        e00 = MFMA16(ah0, ba, e00); e00 = MFMA16(al0, ba, e00);
        e01 = MFMA16(ah1, ba, e01); e01 = MFMA16(al1, ba, e01);
        e10 = MFMA16(ah0, bb, e10); e10 = MFMA16(al0, bb, e10);
        e11 = MFMA16(ah1, bb, e11); e11 = MFMA16(al1, bb, e11);
      }
      ASTORE(e00, e01, wid * 16)                       // cols < 256
      if (wid < 4) ASTORE(e10, e11, (16 + wid) * 16)   // cols 256..319
#undef ASTORE
    }
    __syncthreads();

    // ================= phase F: KG partials (4 waves, k-halves) =================
    if (wid < 4) {
      const int mB = wid & 1, half = wid >> 1;
      f32x4 ka = {0.f, 0.f, 0.f, 0.f};
#pragma unroll
      for (int q = 0; q < 5; ++q) {
        const int kt3 = half * 5 + q;
        const int _o = (kt3 * 2 + mB) * 512 + lane * 8;
        const f16x8 ah = *(const f16x8*)&sAhi[_o];
        const f16x8 al = *(const f16x8*)&sAlo[_o];
        const f16x8 bw = *(const f16x8*)&g_w3[kt3 * 512 + lane * 8];
        ka = MFMA16(ah, bw, ka); ka = MFMA16(al, bw, ka);
      }
      const int c = lane & 15;
      if (c < 8) {
        const int rb = mB * 16 + g4;
#pragma unroll
        for (int reg = 0; reg < 4; ++reg) s_kgp[half][rb + reg][c] = ka[reg];
      }
    }
    __syncthreads();
  }

  // ---- final F2 (t = 31) ----
  {
    float kg[8];
#pragma unroll
    for (int cc = 0; cc < 8; ++cc)
      kg[cc] = s_kgp[0][rl][cc] + s_kgp[1][rl][cc] + s_b3[cc];
#pragma unroll
    for (int m = 0; m < 4; ++m)
      post[m] = prior[m] + kg[2 * m] * d0 + kg[2 * m + 1] * d1;
    if (wid == 0 && lane < 32) {
      float4 o; o.x = post[0]; o.y = post[1]; o.z = post[2]; o.w = post[3];
      *(float4*)&out[((size_t)(T_STEPS - 1) * BATCH + row0 + rl) * 4] = o;
    }
  }
}

}  // namespace

extern "C" void kernel_launch(void* const* d_in, const int* in_sizes, int n_in,
                              void* d_out, int out_size, void* d_ws, size_t ws_size,
                              hipStream_t stream) {
  const float* y   = (const float*)d_in[0];
  const float* Fm  = (const float*)d_in[1];
  const float* Hm  = (const float*)d_in[2];
  const float* W1  = (const float*)d_in[3];
  const float* b1  = (const float*)d_in[4];
  const float* Wg  = (const float*)d_in[5];
  const float* Ug  = (const float*)d_in[6];
  const float* bg  = (const float*)d_in[7];
  const float* W2  = (const float*)d_in[8];
  const float* b2  = (const float*)d_in[9];
  const float* W3  = (const float*)d_in[10];
  const float* b3  = (const float*)d_in[11];
  const float* hn0 = (const float*)d_in[12];
  float* out = (float*)d_out;

  constexpr int PREP_TOT = (NTW1 + NTG * KTG + NT2 * KT2 + KT3) * 512;
  prep_kernel<<<(PREP_TOT + 255) / 256, 256, 0, stream>>>(W1, b1, Wg, Ug, W2, b2, W3);
  knet_kernel<<<BATCH / BR, NTHR, 0, stream>>>(y, Fm, Hm, bg, b3, hn0, out);
}

// Round 5
// 1701.524 us; speedup vs baseline: 2.4184x; 1.1870x over previous
//
#include <hip/hip_runtime.h>

// KalmanNet recurrent step, MFMA fp16, r5: forced 128-VGPR budget, explicit
// B double-buffering, dead-tile trim.
//
// Per block: 32 batch rows, full T=32 recurrence, 1024 threads (16 waves,
// 4/SIMD, exactly specified via amdgpu_waves_per_eu(4,4)). GEMMs on
// v_mfma_f32_16x16x32_f16 with A hi/lo fp16 split (exact activations; only
// weight quantization error). Weights prepacked per launch into fragment
// order (g_w1/g_wcat/g_w2/g_w3, ~1.4 MB, L2-resident).
//
// Gates GEMM [32,704]x[704,600]: 52 REAL j-tiles (13 per group z|r|xh|hh,
// 208-col pad). Wave w (w<13) owns j-tile w of EACH group; per kt: 3 B loads
// (z, r, xh-or-hh; xh kt 0..14 / hh kt 15..21 are k-disjoint), 12 MFMAs,
// with next-kt B prefetched into regs (double-buffer). Waves 13..15 idle in
// phase C (they carried all-zero tiles in r4 -- pure traffic).
// After phase C each lane holds z,r,xh,hh for (row, j=16w+(lane&15)) =>
// in-register GRU; h written back to its A-fragment slots (k=480+j).
//
// Bias folding: W1 GEMM ones-row k=8 carries b1; h-pad k=680 is a permanent
// 1.0 and g_w2 row k_h=200 carries b2 (gates weights at k=680 are zero).
//
// Fragment maps (verified r2-r4): A/B k = kt*32 + (lane>>4)*8 + i,
// A row / B col = lane&15; C/D col = lane&15, row = (lane>>4)*4 + reg.
//
// r5 diagnostic targets: VGPR ~110-128 (was 64), WRITE_SIZE ~5 MB (was
// 164 MB => spills dead), FETCH ~1.9 GB (dead tiles gone).

namespace {

constexpr int T_STEPS = 32;
constexpr int BATCH   = 8192;
constexpr int H1      = 480;
constexpr int HID     = 200;
constexpr int H2      = 320;
constexpr int BR      = 32;    // batch rows per block (2 MFMA m-tiles)
constexpr int NTHR    = 1024;  // 16 waves
constexpr int KTG     = 22;    // gates K tiles (704 = 480 a1 + 224 h/pad)
constexpr int NTG     = 52;    // 4 groups x 13 real j-tiles (208-col pad)
constexpr int NTW1    = 32;    // W1 col tiles (tiles 30,31 zero; loads unguarded)
constexpr int NT2     = 20;    // W2 real col tiles (320/16)
constexpr int KT2     = 7;     // W2 K tiles (224)
constexpr int KT3     = 10;    // W3 K tiles (320)

using f16x8 = __attribute__((ext_vector_type(8))) _Float16;
using f32x4 = __attribute__((ext_vector_type(4))) float;

__device__ _Float16 g_w1[NTW1 * 512];          // [nt][lane][8], k=8 row = b1
__device__ _Float16 g_wcat[NTG * KTG * 512];   // [grp*13+tile][kt][lane][8]
__device__ _Float16 g_w2[NT2 * KT2 * 512];     // [nt][kt][lane][8], k_h=200 = b2
__device__ _Float16 g_w3[KT3 * 512];           // [kt][lane][8], cols 8..15 = 0

#define MFMA16(A, B, C) __builtin_amdgcn_mfma_f32_16x16x32_f16((A), (B), (C), 0, 0, 0)

__device__ __forceinline__ float sigmoid_(float x) { return 1.f / (1.f + __expf(-x)); }
__device__ __forceinline__ float tanh_(float x) {
  x = fminf(fmaxf(x, -15.f), 15.f);
  const float e = __expf(-2.f * x);
  return (1.f - e) / (1.f + e);
}
__device__ __forceinline__ f16x8 f16x8_zero() {
  f16x8 v;
#pragma unroll
  for (int i = 0; i < 8; ++i) v[i] = (_Float16)0.f;
  return v;
}

// element (k, r) -> flat half index in A-fragment LDS layout
// [kt][m=r>>4][lane=((k&31)>>3)*16 + (r&15)][i=k&7]
__device__ __forceinline__ int afrag_off(int k, int r) {
  const int kt = k >> 5, kk = k & 31;
  return ((kt * 2 + (r >> 4)) * 512) + ((((kk >> 3) << 4) | (r & 15)) * 8) + (kk & 7);
}

// ---------------- weight pre-pack ----------------
__global__ __launch_bounds__(256) void prep_kernel(
    const float* __restrict__ W1, const float* __restrict__ b1,
    const float* __restrict__ Wg, const float* __restrict__ Ug,
    const float* __restrict__ W2, const float* __restrict__ b2,
    const float* __restrict__ W3) {
  const int idx = blockIdx.x * 256 + threadIdx.x;
  constexpr int TOTW1 = NTW1 * 512;
  constexpr int TOT1  = NTG * KTG * 512;
  constexpr int TOT2  = NT2 * KT2 * 512;
  constexpr int TOT3  = KT3 * 512;
  if (idx < TOTW1) {
    const int i = idx & 7, l = (idx >> 3) & 63, nt = idx >> 9;
    const int g = l >> 4, c = l & 15;
    const int k = g * 8 + i, col = nt * 16 + c;
    float wv = 0.f;
    if (col < H1) {
      if (k < 8) wv = W1[k * H1 + col];
      else if (k == 8) wv = b1[col];
    }
    g_w1[idx] = (_Float16)wv;
  } else if (idx < TOTW1 + TOT1) {
    const int id = idx - TOTW1;
    const int i = id & 7, l = (id >> 3) & 63, nk = id >> 9;
    const int kt = nk % KTG, nt = nk / KTG;
    const int g = l >> 4, c = l & 15;
    const int k = kt * 32 + g * 8 + i;        // 0..703
    const int grp = nt / 13;                  // 0=z 1=r 2=xh 3=hh
    const int jj = (nt - grp * 13) * 16 + c;  // 0..207
    float wv = 0.f;
    if (jj < HID) {
      if (grp == 0) {
        if (k < H1) wv = Wg[k * 600 + jj];
        else if (k < H1 + HID) wv = Ug[(k - H1) * 600 + jj];
      } else if (grp == 1) {
        if (k < H1) wv = Wg[k * 600 + 200 + jj];
        else if (k < H1 + HID) wv = Ug[(k - H1) * 600 + 200 + jj];
      } else if (grp == 2) {
        if (k < H1) wv = Wg[k * 600 + 400 + jj];           // xh: a1 rows only
      } else {
        if (k >= H1 && k < H1 + HID) wv = Ug[(k - H1) * 600 + 400 + jj];  // hh
      }
    }
    g_wcat[id] = (_Float16)wv;
  } else if (idx < TOTW1 + TOT1 + TOT2) {
    const int id = idx - TOTW1 - TOT1;
    const int i = id & 7, l = (id >> 3) & 63, nk = id >> 9;
    const int kt = nk % KT2, nt = nk / KT2;
    const int g = l >> 4, c = l & 15;
    const int k = kt * 32 + g * 8 + i;        // 0..223
    const int col = nt * 16 + c;              // 0..319 (all real)
    float wv = 0.f;
    if (k < HID) wv = W2[k * H2 + col];
    else if (k == 200) wv = b2[col];          // ones-row at k_h=200 (k=680)
    g_w2[id] = (_Float16)wv;
  } else if (idx < TOTW1 + TOT1 + TOT2 + TOT3) {
    const int id = idx - TOTW1 - TOT1 - TOT2;
    const int i = id & 7, l = (id >> 3) & 63, kt = id >> 9;
    const int g = l >> 4, c = l & 15;
    const int k = kt * 32 + g * 8 + i;        // 0..319
    g_w3[id] = (_Float16)((c < 8) ? W3[k * 8 + c] : 0.f);
  }
}

// ---------------- main recurrent kernel ----------------
__global__
__attribute__((amdgpu_flat_work_group_size(NTHR, NTHR)))
__attribute__((amdgpu_waves_per_eu(4, 4)))
void knet_kernel(
    const float* __restrict__ y,    // [T,B,2]
    const float* __restrict__ Fm,   // [4,4]
    const float* __restrict__ Hm,   // [2,4]
    const float* __restrict__ bg,   // [2,600]
    const float* __restrict__ b3,   // [8]
    const float* __restrict__ hn0,  // [B,200]
    float* __restrict__ out)        // [T,B,4]
{
  // A-fragments of x_cat = [a1(480) | h(200) | 1.0 @680 | 0-pad]; a2 reuses
  // slots 0..9 between phase E and phase F.
  __shared__ alignas(16) _Float16 sAhi[KTG * 2 * 512];   // 45056 B
  __shared__ alignas(16) _Float16 sAlo[KTG * 2 * 512];   // 45056 B
  __shared__ alignas(16) float s_in8T[8][BR];
  __shared__ alignas(16) float s_kgp[2][BR][8];          // KG k-half partials
  __shared__ alignas(16) float s_bias[4][HID];
  __shared__ alignas(16) float s_fh[32];                 // Fm[16], Hm[8]
  __shared__ alignas(16) float s_b3[8];

  const int tid  = threadIdx.x;
  const int lane = tid & 63;
  const int wid  = __builtin_amdgcn_readfirstlane(tid >> 6);  // 0..15
  const int row0 = blockIdx.x * BR;
  const int rl   = lane & 31;
  const int g4   = (lane >> 4) << 2;

  // ---- init ----
  if (tid < HID) {
    s_bias[0][tid] = bg[tid]       + bg[600 + tid];   // z
    s_bias[1][tid] = bg[200 + tid] + bg[800 + tid];   // r
    s_bias[2][tid] = bg[400 + tid];                   // xh (input bias)
    s_bias[3][tid] = bg[1000 + tid];                  // hh (recurrent bias)
  }
  if (tid < 16) s_fh[tid] = Fm[tid];
  else if (tid < 24) s_fh[tid] = Hm[tid - 16];
  if (tid < 8) s_b3[tid] = b3[tid];
  for (int e = tid; e < HID * BR; e += NTHR) {
    const int j = e >> 5, r = e & 31;
    const float h0 = hn0[(size_t)(row0 + r) * HID + j];
    const int off = afrag_off(480 + j, r);
    const _Float16 hi = (_Float16)h0;
    sAhi[off] = hi;
    sAlo[off] = (_Float16)(h0 - (float)hi);
  }
  for (int e = tid; e < 24 * BR; e += NTHR) {   // k 680..703: 1.0 then zeros
    const int k = 680 + (e >> 5), r = e & 31;
    const int off = afrag_off(k, r);
    sAhi[off] = (_Float16)((k == 680) ? 1.f : 0.f);
    sAlo[off] = (_Float16)0.f;
  }
  __syncthreads();

  // persistent per-lane state (row rl)
  float prior[4] = {0.f, 0.f, 0.f, 0.f};
  float post[4]  = {0.f, 0.f, 0.f, 0.f};
  float d0 = 0.f, d1 = 0.f;

  for (int t = 0; t < T_STEPS; ++t) {
    // ================= phase 1: F2(t-1) + A(t) + W1-GEMM(t) =================
    if (t > 0) {
      float kg[8];
#pragma unroll
      for (int cc = 0; cc < 8; ++cc)
        kg[cc] = s_kgp[0][rl][cc] + s_kgp[1][rl][cc] + s_b3[cc];
#pragma unroll
      for (int m = 0; m < 4; ++m)
        post[m] = prior[m] + kg[2 * m] * d0 + kg[2 * m + 1] * d1;
      if (wid == 0 && lane < 32) {
        float4 o; o.x = post[0]; o.y = post[1]; o.z = post[2]; o.w = post[3];
        *(float4*)&out[((size_t)(t - 1) * BATCH + row0 + rl) * 4] = o;
      }
    }
    {   // ---- A: prior / innovation / features (redundant per wave) ----
      float opri[4], np[4];
#pragma unroll
      for (int m = 0; m < 4; ++m) opri[m] = prior[m];
#pragma unroll
      for (int m = 0; m < 4; ++m) {
        float s = 0.f;
#pragma unroll
        for (int j = 0; j < 4; ++j) s += s_fh[m * 4 + j] * post[j];
        np[m] = s;
      }
      float m0 = 0.f, m1 = 0.f;
#pragma unroll
      for (int m = 0; m < 4; ++m) { m0 += s_fh[16 + m] * np[m]; m1 += s_fh[20 + m] * np[m]; }
      const float2 yv = *(const float2*)&y[((size_t)t * BATCH + row0 + rl) * 2];
      d0 = yv.x - m0;
      d1 = yv.y - m1;
      float dx[4], ssx = 0.f;
#pragma unroll
      for (int m = 0; m < 4; ++m) { dx[m] = post[m] - opri[m]; ssx += dx[m] * dx[m]; }
      const float idx_ = rsqrtf(fmaxf(ssx, 1e-12f));
      const float idy_ = rsqrtf(fmaxf(d0 * d0 + d1 * d1, 1e-12f));
#pragma unroll
      for (int m = 0; m < 4; ++m) prior[m] = np[m];
      if (lane < 32) {
        const float n0 = d0 * idy_, n1 = d1 * idy_;
        s_in8T[0][rl] = n0; s_in8T[1][rl] = n1;
        s_in8T[2][rl] = n0; s_in8T[3][rl] = n1;
#pragma unroll
        for (int m = 0; m < 4; ++m) s_in8T[4 + m][rl] = dx[m] * idx_;
      }
    }
    {   // ---- W1-GEMM: a1 = relu([in8,1] @ [W1;b1]), 2 tiles/wave ----
      f16x8 ah0 = f16x8_zero(), al0 = f16x8_zero();
      f16x8 ah1 = f16x8_zero(), al1 = f16x8_zero();
      const int g = lane >> 4, c = lane & 15;
      if (g == 0) {
#pragma unroll
        for (int i = 0; i < 8; ++i) {
          const float v0 = s_in8T[i][c];
          const float v1 = s_in8T[i][c + 16];
          const _Float16 h0 = (_Float16)v0; ah0[i] = h0; al0[i] = (_Float16)(v0 - (float)h0);
          const _Float16 h1 = (_Float16)v1; ah1[i] = h1; al1[i] = (_Float16)(v1 - (float)h1);
        }
      } else if (g == 1) {
        ah0[0] = (_Float16)1.f;   // ones-row k=8 -> b1
        ah1[0] = (_Float16)1.f;
      }
      f32x4 p00 = {0.f, 0.f, 0.f, 0.f}, p01 = p00, p10 = p00, p11 = p00;
      const f16x8 w1a = *(const f16x8*)&g_w1[(size_t)wid * 512 + lane * 8];
      const f16x8 w1b = *(const f16x8*)&g_w1[(size_t)(16 + wid) * 512 + lane * 8];
      p00 = MFMA16(ah0, w1a, p00); p00 = MFMA16(al0, w1a, p00);
      p01 = MFMA16(ah1, w1a, p01); p01 = MFMA16(al1, w1a, p01);
      p10 = MFMA16(ah0, w1b, p10); p10 = MFMA16(al0, w1b, p10);
      p11 = MFMA16(ah1, w1b, p11); p11 = MFMA16(al1, w1b, p11);
#define ASTORE(A0, A1, COLBASE)                                      \
      { const int col = (COLBASE) + (lane & 15);                     \
        _Pragma("unroll")                                            \
        for (int reg = 0; reg < 4; ++reg) {                          \
          const float v0 = fmaxf(A0[reg], 0.f);                      \
          const float v1 = fmaxf(A1[reg], 0.f);                      \
          const int o0 = afrag_off(col, g4 + reg);                   \
          const int o1 = afrag_off(col, 16 + g4 + reg);              \
          const _Float16 q0 = (_Float16)v0, q1 = (_Float16)v1;       \
          sAhi[o0] = q0; sAlo[o0] = (_Float16)(v0 - (float)q0);      \
          sAhi[o1] = q1; sAlo[o1] = (_Float16)(v1 - (float)q1);      \
        } }
      ASTORE(p00, p01, wid * 16)
      if (wid < 14) ASTORE(p10, p11, (16 + wid) * 16)
    }
    __syncthreads();

    // ================= phase C: gates GEMM (waves 0..12, B dbuf) =================
    f32x4 aZ0 = {0.f, 0.f, 0.f, 0.f}, aZ1 = aZ0, aR0 = aZ0, aR1 = aZ0;
    f32x4 aX0 = aZ0, aX1 = aZ0, aH0 = aZ0, aH1 = aZ0;
    if (wid < 13) {
      const _Float16* bzp = g_wcat + ((size_t)(0  + wid) * KTG) * 512 + lane * 8;
      const _Float16* brp = g_wcat + ((size_t)(13 + wid) * KTG) * 512 + lane * 8;
      const _Float16* bxp = g_wcat + ((size_t)(26 + wid) * KTG) * 512 + lane * 8;
      const _Float16* bhp = g_wcat + ((size_t)(39 + wid) * KTG) * 512 + lane * 8;
      f16x8 bzC = *(const f16x8*)(bzp);
      f16x8 brC = *(const f16x8*)(brp);
      f16x8 bxC = *(const f16x8*)(bxp);
#pragma unroll
      for (int kt = 0; kt < KTG; ++kt) {
        f16x8 bzN, brN, bxN;
        if (kt + 1 < KTG) {          // prefetch next kt's B fragments
          bzN = *(const f16x8*)(bzp + (kt + 1) * 512);
          brN = *(const f16x8*)(brp + (kt + 1) * 512);
          bxN = (kt + 1 < 15) ? *(const f16x8*)(bxp + (kt + 1) * 512)
                              : *(const f16x8*)(bhp + (kt + 1) * 512);
        }
        const int _o = kt * 1024 + lane * 8;
        const f16x8 ah0 = *(const f16x8*)&sAhi[_o];
        const f16x8 al0 = *(const f16x8*)&sAlo[_o];
        const f16x8 ah1 = *(const f16x8*)&sAhi[_o + 512];
        const f16x8 al1 = *(const f16x8*)&sAlo[_o + 512];
        aZ0 = MFMA16(ah0, bzC, aZ0);  aZ0 = MFMA16(al0, bzC, aZ0);
        aZ1 = MFMA16(ah1, bzC, aZ1);  aZ1 = MFMA16(al1, bzC, aZ1);
        aR0 = MFMA16(ah0, brC, aR0);  aR0 = MFMA16(al0, brC, aR0);
        aR1 = MFMA16(ah1, brC, aR1);  aR1 = MFMA16(al1, brC, aR1);
        if (kt < 15) {
          aX0 = MFMA16(ah0, bxC, aX0); aX0 = MFMA16(al0, bxC, aX0);
          aX1 = MFMA16(ah1, bxC, aX1); aX1 = MFMA16(al1, bxC, aX1);
        } else {
          aH0 = MFMA16(ah0, bxC, aH0); aH0 = MFMA16(al0, bxC, aH0);
          aH1 = MFMA16(ah1, bxC, aH1); aH1 = MFMA16(al1, bxC, aH1);
        }
        if (kt + 1 < KTG) { bzC = bzN; brC = brN; bxC = bxN; }
      }
    }
    __syncthreads();   // all h reads done before in-place h update

    // ================= phase D': in-register GRU update =================
    if (wid < 13) {
      const int c = lane & 15;
      const int j = wid * 16 + c;
      if (j < HID) {
        const float bz  = s_bias[0][j], brb = s_bias[1][j];
        const float bxh = s_bias[2][j], bhh = s_bias[3][j];
#define GRU1(AZ, AR, AX, AH, MB)                                         \
        _Pragma("unroll")                                                \
        for (int reg = 0; reg < 4; ++reg) {                              \
          const int r = (MB) * 16 + g4 + reg;                            \
          const int off = afrag_off(480 + j, r);                         \
          const float hold = (float)sAhi[off] + (float)sAlo[off];        \
          const float z  = sigmoid_(AZ[reg] + bz);                       \
          const float rr = sigmoid_(AR[reg] + brb);                      \
          const float hc = tanh_((AX[reg] + bxh) + rr * (AH[reg] + bhh));\
          const float hn = z * hold + (1.f - z) * hc;                    \
          const _Float16 qh = (_Float16)hn;                              \
          sAhi[off] = qh;                                                \
          sAlo[off] = (_Float16)(hn - (float)qh);                       \
        }
        GRU1(aZ0, aR0, aX0, aH0, 0)
        GRU1(aZ1, aR1, aX1, aH1, 1)
#undef GRU1
      }
    }
    __syncthreads();

    // ================= phase E: a2 = relu(h @ W2 + b2), B dbuf =================
    {
      f32x4 e00 = {0.f, 0.f, 0.f, 0.f}, e01 = e00, e10 = e00, e11 = e00;
      const _Float16* w2a = g_w2 + ((size_t)wid * KT2) * 512 + lane * 8;
      const _Float16* w2b = g_w2 + ((size_t)(16 + wid) * KT2) * 512 + lane * 8;
      f16x8 baC = *(const f16x8*)(w2a);
      f16x8 bbC = (wid < 4) ? *(const f16x8*)(w2b) : f16x8_zero();
#pragma unroll
      for (int qt = 0; qt < KT2; ++qt) {
        f16x8 baN, bbN;
        if (qt + 1 < KT2) {
          baN = *(const f16x8*)(w2a + (qt + 1) * 512);
          if (wid < 4) bbN = *(const f16x8*)(w2b + (qt + 1) * 512);
        }
        const int _o = (15 + qt) * 1024 + lane * 8;
        const f16x8 ah0 = *(const f16x8*)&sAhi[_o];
        const f16x8 al0 = *(const f16x8*)&sAlo[_o];
        const f16x8 ah1 = *(const f16x8*)&sAhi[_o + 512];
        const f16x8 al1 = *(const f16x8*)&sAlo[_o + 512];
        e00 = MFMA16(ah0, baC, e00); e00 = MFMA16(al0, baC, e00);
        e01 = MFMA16(ah1, baC, e01); e01 = MFMA16(al1, baC, e01);
        if (wid < 4) {
          e10 = MFMA16(ah0, bbC, e10); e10 = MFMA16(al0, bbC, e10);
          e11 = MFMA16(ah1, bbC, e11); e11 = MFMA16(al1, bbC, e11);
        }
        if (qt + 1 < KT2) { baC = baN; if (wid < 4) bbC = bbN; }
      }
      ASTORE(e00, e01, wid * 16)                       // cols < 256
      if (wid < 4) ASTORE(e10, e11, (16 + wid) * 16)   // cols 256..319
#undef ASTORE
    }
    __syncthreads();

    // ================= phase F: KG partials (4 waves, k-halves) =================
    if (wid < 4) {
      const int mB = wid & 1, half = wid >> 1;
      f32x4 ka = {0.f, 0.f, 0.f, 0.f};
      const _Float16* w3p = g_w3 + lane * 8;
      f16x8 bwC = *(const f16x8*)(w3p + (half * 5) * 512);
#pragma unroll
      for (int q = 0; q < 5; ++q) {
        const int kt3 = half * 5 + q;
        f16x8 bwN;
        if (q + 1 < 5) bwN = *(const f16x8*)(w3p + (kt3 + 1) * 512);
        const int _o = (kt3 * 2 + mB) * 512 + lane * 8;
        const f16x8 ah = *(const f16x8*)&sAhi[_o];
        const f16x8 al = *(const f16x8*)&sAlo[_o];
        ka = MFMA16(ah, bwC, ka); ka = MFMA16(al, bwC, ka);
        if (q + 1 < 5) bwC = bwN;
      }
      const int c = lane & 15;
      if (c < 8) {
        const int rb = mB * 16 + g4;
#pragma unroll
        for (int reg = 0; reg < 4; ++reg) s_kgp[half][rb + reg][c] = ka[reg];
      }
    }
    __syncthreads();
  }

  // ---- final F2 (t = 31) ----
  {
    float kg[8];
#pragma unroll
    for (int cc = 0; cc < 8; ++cc)
      kg[cc] = s_kgp[0][rl][cc] + s_kgp[1][rl][cc] + s_b3[cc];
#pragma unroll
    for (int m = 0; m < 4; ++m)
      post[m] = prior[m] + kg[2 * m] * d0 + kg[2 * m + 1] * d1;
    if (wid == 0 && lane < 32) {
      float4 o; o.x = post[0]; o.y = post[1]; o.z = post[2]; o.w = post[3];
      *(float4*)&out[((size_t)(T_STEPS - 1) * BATCH + row0 + rl) * 4] = o;
    }
  }
}

}  // namespace

extern "C" void kernel_launch(void* const* d_in, const int* in_sizes, int n_in,
                              void* d_out, int out_size, void* d_ws, size_t ws_size,
                              hipStream_t stream) {
  const float* y   = (const float*)d_in[0];
  const float* Fm  = (const float*)d_in[1];
  const float* Hm  = (const float*)d_in[2];
  const float* W1  = (const float*)d_in[3];
  const float* b1  = (const float*)d_in[4];
  const float* Wg  = (const float*)d_in[5];
  const float* Ug  = (const float*)d_in[6];
  const float* bg  = (const float*)d_in[7];
  const float* W2  = (const float*)d_in[8];
  const float* b2  = (const float*)d_in[9];
  const float* W3  = (const float*)d_in[10];
  const float* b3  = (const float*)d_in[11];
  const float* hn0 = (const float*)d_in[12];
  float* out = (float*)d_out;

  constexpr int PREP_TOT = (NTW1 + NTG * KTG + NT2 * KT2 + KT3) * 512;
  prep_kernel<<<(PREP_TOT + 255) / 256, 256, 0, stream>>>(W1, b1, Wg, Ug, W2, b2, W3);
  knet_kernel<<<BATCH / BR, NTHR, 0, stream>>>(y, Fm, Hm, bg, b3, hn0, out);
}

// Round 6
// 1507.836 us; speedup vs baseline: 2.7291x; 1.1285x over previous
//
#include <hip/hip_runtime.h>

// KalmanNet recurrent step, MFMA fp16, r6: pinned software pipelining.
//
// r5 post-mortem: VGPR_Count stayed 64 (allocator needed no more) => the
// scheduler SANK the source-level B prefetches to their use sites, exposing
// full L2/L3 latency every kt (22 dependent rounds in phase C). r6 pins the
// issue order with __builtin_amdgcn_sched_barrier(0): per kt, issue A(kt+1)
// LDS reads + B(kt+2) global loads, THEN the kt MFMA cluster. Loads get
// >=1-2 MFMA phases (~230-460 cyc) of cover. Same in phase E; light pin in F.
//
// Structure (unchanged from r5): 32 rows/block, T=32 recurrence in-kernel,
// 1024 threads (16 waves, 4/SIMD via waves_per_eu(4,4)). GEMMs on
// v_mfma_f32_16x16x32_f16, A split hi/lo fp16 (exact activations; only
// fp16 weight quantization error). Weights prepacked to fragment order
// (~1.2 MB, L2-resident). Gates GEMM: 52 real j-tiles (13/group z|r|xh|hh),
// wave w<13 owns j-tile w of each group; per kt: 3 B loads, 12 MFMAs; xh
// kt 0..14 / hh kt 15..21 (k-disjoint, tile-aligned boundary). GRU update
// in registers; h lives in A-fragment slots k=480+j. Bias folding: W1 GEMM
// ones-row k=8 carries b1; h-pad k=680 == 1.0 carries b2 via g_w2 row 200.
//
// Fragment maps (verified r2-r5): A/B k = kt*32 + (lane>>4)*8 + i,
// A row / B col = lane&15; C/D col = lane&15, row = (lane>>4)*4 + reg.

namespace {

constexpr int T_STEPS = 32;
constexpr int BATCH   = 8192;
constexpr int H1      = 480;
constexpr int HID     = 200;
constexpr int H2      = 320;
constexpr int BR      = 32;    // batch rows per block (2 MFMA m-tiles)
constexpr int NTHR    = 1024;  // 16 waves
constexpr int KTG     = 22;    // gates K tiles (704 = 480 a1 + 224 h/pad)
constexpr int NTG     = 52;    // 4 groups x 13 real j-tiles
constexpr int NTW1    = 32;    // W1 col tiles
constexpr int NT2     = 20;    // W2 real col tiles (320/16)
constexpr int KT2     = 7;     // W2 K tiles (224)
constexpr int KT3     = 10;    // W3 K tiles (320)

using f16x8 = __attribute__((ext_vector_type(8))) _Float16;
using f32x4 = __attribute__((ext_vector_type(4))) float;

__device__ _Float16 g_w1[NTW1 * 512];          // [nt][lane][8], k=8 row = b1
__device__ _Float16 g_wcat[NTG * KTG * 512];   // [grp*13+tile][kt][lane][8]
__device__ _Float16 g_w2[NT2 * KT2 * 512];     // [nt][kt][lane][8], k_h=200 = b2
__device__ _Float16 g_w3[KT3 * 512];           // [kt][lane][8], cols 8..15 = 0

#define MFMA16(A, B, C) __builtin_amdgcn_mfma_f32_16x16x32_f16((A), (B), (C), 0, 0, 0)
#define SBAR() __builtin_amdgcn_sched_barrier(0)

__device__ __forceinline__ float sigmoid_(float x) { return 1.f / (1.f + __expf(-x)); }
__device__ __forceinline__ float tanh_(float x) {
  x = fminf(fmaxf(x, -15.f), 15.f);
  const float e = __expf(-2.f * x);
  return (1.f - e) / (1.f + e);
}
__device__ __forceinline__ f16x8 f16x8_zero() {
  f16x8 v;
#pragma unroll
  for (int i = 0; i < 8; ++i) v[i] = (_Float16)0.f;
  return v;
}

// element (k, r) -> flat half index in A-fragment LDS layout
// [kt][m=r>>4][lane=((k&31)>>3)*16 + (r&15)][i=k&7]
__device__ __forceinline__ int afrag_off(int k, int r) {
  const int kt = k >> 5, kk = k & 31;
  return ((kt * 2 + (r >> 4)) * 512) + ((((kk >> 3) << 4) | (r & 15)) * 8) + (kk & 7);
}

// ---------------- weight pre-pack ----------------
__global__ __launch_bounds__(256) void prep_kernel(
    const float* __restrict__ W1, const float* __restrict__ b1,
    const float* __restrict__ Wg, const float* __restrict__ Ug,
    const float* __restrict__ W2, const float* __restrict__ b2,
    const float* __restrict__ W3) {
  const int idx = blockIdx.x * 256 + threadIdx.x;
  constexpr int TOTW1 = NTW1 * 512;
  constexpr int TOT1  = NTG * KTG * 512;
  constexpr int TOT2  = NT2 * KT2 * 512;
  constexpr int TOT3  = KT3 * 512;
  if (idx < TOTW1) {
    const int i = idx & 7, l = (idx >> 3) & 63, nt = idx >> 9;
    const int g = l >> 4, c = l & 15;
    const int k = g * 8 + i, col = nt * 16 + c;
    float wv = 0.f;
    if (col < H1) {
      if (k < 8) wv = W1[k * H1 + col];
      else if (k == 8) wv = b1[col];
    }
    g_w1[idx] = (_Float16)wv;
  } else if (idx < TOTW1 + TOT1) {
    const int id = idx - TOTW1;
    const int i = id & 7, l = (id >> 3) & 63, nk = id >> 9;
    const int kt = nk % KTG, nt = nk / KTG;
    const int g = l >> 4, c = l & 15;
    const int k = kt * 32 + g * 8 + i;        // 0..703
    const int grp = nt / 13;                  // 0=z 1=r 2=xh 3=hh
    const int jj = (nt - grp * 13) * 16 + c;  // 0..207
    float wv = 0.f;
    if (jj < HID) {
      if (grp == 0) {
        if (k < H1) wv = Wg[k * 600 + jj];
        else if (k < H1 + HID) wv = Ug[(k - H1) * 600 + jj];
      } else if (grp == 1) {
        if (k < H1) wv = Wg[k * 600 + 200 + jj];
        else if (k < H1 + HID) wv = Ug[(k - H1) * 600 + 200 + jj];
      } else if (grp == 2) {
        if (k < H1) wv = Wg[k * 600 + 400 + jj];           // xh: a1 rows only
      } else {
        if (k >= H1 && k < H1 + HID) wv = Ug[(k - H1) * 600 + 400 + jj];  // hh
      }
    }
    g_wcat[id] = (_Float16)wv;
  } else if (idx < TOTW1 + TOT1 + TOT2) {
    const int id = idx - TOTW1 - TOT1;
    const int i = id & 7, l = (id >> 3) & 63, nk = id >> 9;
    const int kt = nk % KT2, nt = nk / KT2;
    const int g = l >> 4, c = l & 15;
    const int k = kt * 32 + g * 8 + i;        // 0..223
    const int col = nt * 16 + c;              // 0..319 (all real)
    float wv = 0.f;
    if (k < HID) wv = W2[k * H2 + col];
    else if (k == 200) wv = b2[col];          // ones-row at k_h=200 (k=680)
    g_w2[id] = (_Float16)wv;
  } else if (idx < TOTW1 + TOT1 + TOT2 + TOT3) {
    const int id = idx - TOTW1 - TOT1 - TOT2;
    const int i = id & 7, l = (id >> 3) & 63, kt = id >> 9;
    const int g = l >> 4, c = l & 15;
    const int k = kt * 32 + g * 8 + i;        // 0..319
    g_w3[id] = (_Float16)((c < 8) ? W3[k * 8 + c] : 0.f);
  }
}

// ---------------- main recurrent kernel ----------------
__global__
__attribute__((amdgpu_flat_work_group_size(NTHR, NTHR)))
__attribute__((amdgpu_waves_per_eu(4, 4)))
void knet_kernel(
    const float* __restrict__ y,    // [T,B,2]
    const float* __restrict__ Fm,   // [4,4]
    const float* __restrict__ Hm,   // [2,4]
    const float* __restrict__ bg,   // [2,600]
    const float* __restrict__ b3,   // [8]
    const float* __restrict__ hn0,  // [B,200]
    float* __restrict__ out)        // [T,B,4]
{
  // A-fragments of x_cat = [a1(480) | h(200) | 1.0 @680 | 0-pad]; a2 reuses
  // slots 0..9 between phase E and phase F.
  __shared__ alignas(16) _Float16 sAhi[KTG * 2 * 512];   // 45056 B
  __shared__ alignas(16) _Float16 sAlo[KTG * 2 * 512];   // 45056 B
  __shared__ alignas(16) float s_in8T[8][BR];
  __shared__ alignas(16) float s_kgp[2][BR][8];          // KG k-half partials
  __shared__ alignas(16) float s_bias[4][HID];
  __shared__ alignas(16) float s_fh[32];                 // Fm[16], Hm[8]
  __shared__ alignas(16) float s_b3[8];

  const int tid  = threadIdx.x;
  const int lane = tid & 63;
  const int wid  = __builtin_amdgcn_readfirstlane(tid >> 6);  // 0..15
  const int row0 = blockIdx.x * BR;
  const int rl   = lane & 31;
  const int g4   = (lane >> 4) << 2;

  // ---- init ----
  if (tid < HID) {
    s_bias[0][tid] = bg[tid]       + bg[600 + tid];   // z
    s_bias[1][tid] = bg[200 + tid] + bg[800 + tid];   // r
    s_bias[2][tid] = bg[400 + tid];                   // xh (input bias)
    s_bias[3][tid] = bg[1000 + tid];                  // hh (recurrent bias)
  }
  if (tid < 16) s_fh[tid] = Fm[tid];
  else if (tid < 24) s_fh[tid] = Hm[tid - 16];
  if (tid < 8) s_b3[tid] = b3[tid];
  for (int e = tid; e < HID * BR; e += NTHR) {
    const int j = e >> 5, r = e & 31;
    const float h0 = hn0[(size_t)(row0 + r) * HID + j];
    const int off = afrag_off(480 + j, r);
    const _Float16 hi = (_Float16)h0;
    sAhi[off] = hi;
    sAlo[off] = (_Float16)(h0 - (float)hi);
  }
  for (int e = tid; e < 24 * BR; e += NTHR) {   // k 680..703: 1.0 then zeros
    const int k = 680 + (e >> 5), r = e & 31;
    const int off = afrag_off(k, r);
    sAhi[off] = (_Float16)((k == 680) ? 1.f : 0.f);
    sAlo[off] = (_Float16)0.f;
  }
  __syncthreads();

  // persistent per-lane state (row rl)
  float prior[4] = {0.f, 0.f, 0.f, 0.f};
  float post[4]  = {0.f, 0.f, 0.f, 0.f};
  float d0 = 0.f, d1 = 0.f;

  for (int t = 0; t < T_STEPS; ++t) {
    // ================= phase 1: F2(t-1) + A(t) + W1-GEMM(t) =================
    if (t > 0) {
      float kg[8];
#pragma unroll
      for (int cc = 0; cc < 8; ++cc)
        kg[cc] = s_kgp[0][rl][cc] + s_kgp[1][rl][cc] + s_b3[cc];
#pragma unroll
      for (int m = 0; m < 4; ++m)
        post[m] = prior[m] + kg[2 * m] * d0 + kg[2 * m + 1] * d1;
      if (wid == 0 && lane < 32) {
        float4 o; o.x = post[0]; o.y = post[1]; o.z = post[2]; o.w = post[3];
        *(float4*)&out[((size_t)(t - 1) * BATCH + row0 + rl) * 4] = o;
      }
    }
    {   // ---- A: prior / innovation / features (redundant per wave) ----
      float opri[4], np[4];
#pragma unroll
      for (int m = 0; m < 4; ++m) opri[m] = prior[m];
#pragma unroll
      for (int m = 0; m < 4; ++m) {
        float s = 0.f;
#pragma unroll
        for (int j = 0; j < 4; ++j) s += s_fh[m * 4 + j] * post[j];
        np[m] = s;
      }
      float m0 = 0.f, m1 = 0.f;
#pragma unroll
      for (int m = 0; m < 4; ++m) { m0 += s_fh[16 + m] * np[m]; m1 += s_fh[20 + m] * np[m]; }
      const float2 yv = *(const float2*)&y[((size_t)t * BATCH + row0 + rl) * 2];
      d0 = yv.x - m0;
      d1 = yv.y - m1;
      float dx[4], ssx = 0.f;
#pragma unroll
      for (int m = 0; m < 4; ++m) { dx[m] = post[m] - opri[m]; ssx += dx[m] * dx[m]; }
      const float idx_ = rsqrtf(fmaxf(ssx, 1e-12f));
      const float idy_ = rsqrtf(fmaxf(d0 * d0 + d1 * d1, 1e-12f));
#pragma unroll
      for (int m = 0; m < 4; ++m) prior[m] = np[m];
      if (lane < 32) {
        const float n0 = d0 * idy_, n1 = d1 * idy_;
        s_in8T[0][rl] = n0; s_in8T[1][rl] = n1;
        s_in8T[2][rl] = n0; s_in8T[3][rl] = n1;
#pragma unroll
        for (int m = 0; m < 4; ++m) s_in8T[4 + m][rl] = dx[m] * idx_;
      }
    }
    {   // ---- W1-GEMM: a1 = relu([in8,1] @ [W1;b1]), 2 tiles/wave ----
      f16x8 ah0 = f16x8_zero(), al0 = f16x8_zero();
      f16x8 ah1 = f16x8_zero(), al1 = f16x8_zero();
      const int g = lane >> 4, c = lane & 15;
      if (g == 0) {
#pragma unroll
        for (int i = 0; i < 8; ++i) {
          const float v0 = s_in8T[i][c];
          const float v1 = s_in8T[i][c + 16];
          const _Float16 h0 = (_Float16)v0; ah0[i] = h0; al0[i] = (_Float16)(v0 - (float)h0);
          const _Float16 h1 = (_Float16)v1; ah1[i] = h1; al1[i] = (_Float16)(v1 - (float)h1);
        }
      } else if (g == 1) {
        ah0[0] = (_Float16)1.f;   // ones-row k=8 -> b1
        ah1[0] = (_Float16)1.f;
      }
      f32x4 p00 = {0.f, 0.f, 0.f, 0.f}, p01 = p00, p10 = p00, p11 = p00;
      const f16x8 w1a = *(const f16x8*)&g_w1[(size_t)wid * 512 + lane * 8];
      const f16x8 w1b = *(const f16x8*)&g_w1[(size_t)(16 + wid) * 512 + lane * 8];
      p00 = MFMA16(ah0, w1a, p00); p00 = MFMA16(al0, w1a, p00);
      p01 = MFMA16(ah1, w1a, p01); p01 = MFMA16(al1, w1a, p01);
      p10 = MFMA16(ah0, w1b, p10); p10 = MFMA16(al0, w1b, p10);
      p11 = MFMA16(ah1, w1b, p11); p11 = MFMA16(al1, w1b, p11);
#define ASTORE(A0, A1, COLBASE)                                      \
      { const int col = (COLBASE) + (lane & 15);                     \
        _Pragma("unroll")                                            \
        for (int reg = 0; reg < 4; ++reg) {                          \
          const float v0 = fmaxf(A0[reg], 0.f);                      \
          const float v1 = fmaxf(A1[reg], 0.f);                      \
          const int o0 = afrag_off(col, g4 + reg);                   \
          const int o1 = afrag_off(col, 16 + g4 + reg);              \
          const _Float16 q0 = (_Float16)v0, q1 = (_Float16)v1;       \
          sAhi[o0] = q0; sAlo[o0] = (_Float16)(v0 - (float)q0);      \
          sAhi[o1] = q1; sAlo[o1] = (_Float16)(v1 - (float)q1);      \
        } }
      ASTORE(p00, p01, wid * 16)
      if (wid < 14) ASTORE(p10, p11, (16 + wid) * 16)
    }
    __syncthreads();

    // ========== phase C: gates GEMM (waves 0..12, pinned pipeline) ==========
    f32x4 aZ0 = {0.f, 0.f, 0.f, 0.f}, aZ1 = aZ0, aR0 = aZ0, aR1 = aZ0;
    f32x4 aX0 = aZ0, aX1 = aZ0, aH0 = aZ0, aH1 = aZ0;
    if (wid < 13) {
      const _Float16* bzp = g_wcat + ((size_t)(0  + wid) * KTG) * 512 + lane * 8;
      const _Float16* brp = g_wcat + ((size_t)(13 + wid) * KTG) * 512 + lane * 8;
      const _Float16* bxp = g_wcat + ((size_t)(26 + wid) * KTG) * 512 + lane * 8;
      const _Float16* bhp = g_wcat + ((size_t)(39 + wid) * KTG) * 512 + lane * 8;
#define LD3(KT) (((KT) < 15) ? *(const f16x8*)(bxp + (KT) * 512) \
                             : *(const f16x8*)(bhp + (KT) * 512))
      const int ab = lane * 8;
      // prologue: B for kt=0,1; A for kt=0
      f16x8 bz0 = *(const f16x8*)(bzp);
      f16x8 br0 = *(const f16x8*)(brp);
      f16x8 bx0 = LD3(0);
      f16x8 bz1 = *(const f16x8*)(bzp + 512);
      f16x8 br1 = *(const f16x8*)(brp + 512);
      f16x8 bx1 = LD3(1);
      f16x8 cah0 = *(const f16x8*)&sAhi[ab];
      f16x8 cal0 = *(const f16x8*)&sAlo[ab];
      f16x8 cah1 = *(const f16x8*)&sAhi[ab + 512];
      f16x8 cal1 = *(const f16x8*)&sAlo[ab + 512];
#pragma unroll
      for (int kt = 0; kt < KTG; ++kt) {
        f16x8 nah0, nal0, nah1, nal1;
        f16x8 bz2, br2, bx2;
        if (kt + 1 < KTG) {            // issue A(kt+1) LDS reads
          const int o2 = (kt + 1) * 1024 + ab;
          nah0 = *(const f16x8*)&sAhi[o2];
          nal0 = *(const f16x8*)&sAlo[o2];
          nah1 = *(const f16x8*)&sAhi[o2 + 512];
          nal1 = *(const f16x8*)&sAlo[o2 + 512];
        }
        if (kt + 2 < KTG) {            // issue B(kt+2) global loads
          bz2 = *(const f16x8*)(bzp + (kt + 2) * 512);
          br2 = *(const f16x8*)(brp + (kt + 2) * 512);
          bx2 = LD3(kt + 2);
        }
        SBAR();                         // pin: loads issue BEFORE kt's MFMAs
        aZ0 = MFMA16(cah0, bz0, aZ0);  aZ0 = MFMA16(cal0, bz0, aZ0);
        aZ1 = MFMA16(cah1, bz0, aZ1);  aZ1 = MFMA16(cal1, bz0, aZ1);
        aR0 = MFMA16(cah0, br0, aR0);  aR0 = MFMA16(cal0, br0, aR0);
        aR1 = MFMA16(cah1, br0, aR1);  aR1 = MFMA16(cal1, br0, aR1);
        if (kt < 15) {
          aX0 = MFMA16(cah0, bx0, aX0); aX0 = MFMA16(cal0, bx0, aX0);
          aX1 = MFMA16(cah1, bx0, aX1); aX1 = MFMA16(cal1, bx0, aX1);
        } else {
          aH0 = MFMA16(cah0, bx0, aH0); aH0 = MFMA16(cal0, bx0, aH0);
          aH1 = MFMA16(cah1, bx0, aH1); aH1 = MFMA16(cal1, bx0, aH1);
        }
        if (kt + 1 < KTG) { cah0 = nah0; cal0 = nal0; cah1 = nah1; cal1 = nal1; }
        bz0 = bz1; br0 = br1; bx0 = bx1;
        if (kt + 2 < KTG) { bz1 = bz2; br1 = br2; bx1 = bx2; }
      }
#undef LD3
    }
    __syncthreads();   // all h reads done before in-place h update

    // ================= phase D': in-register GRU update =================
    if (wid < 13) {
      const int c = lane & 15;
      const int j = wid * 16 + c;
      if (j < HID) {
        const float bz  = s_bias[0][j], brb = s_bias[1][j];
        const float bxh = s_bias[2][j], bhh = s_bias[3][j];
#define GRU1(AZ, AR, AX, AH, MB)                                         \
        _Pragma("unroll")                                                \
        for (int reg = 0; reg < 4; ++reg) {                              \
          const int r = (MB) * 16 + g4 + reg;                            \
          const int off = afrag_off(480 + j, r);                         \
          const float hold = (float)sAhi[off] + (float)sAlo[off];        \
          const float z  = sigmoid_(AZ[reg] + bz);                       \
          const float rr = sigmoid_(AR[reg] + brb);                      \
          const float hc = tanh_((AX[reg] + bxh) + rr * (AH[reg] + bhh));\
          const float hn = z * hold + (1.f - z) * hc;                    \
          const _Float16 qh = (_Float16)hn;                              \
          sAhi[off] = qh;                                                \
          sAlo[off] = (_Float16)(hn - (float)qh);                       \
        }
        GRU1(aZ0, aR0, aX0, aH0, 0)
        GRU1(aZ1, aR1, aX1, aH1, 1)
#undef GRU1
      }
    }
    __syncthreads();

    // ========== phase E: a2 = relu(h @ W2 + b2), pinned pipeline ==========
    {
      f32x4 e00 = {0.f, 0.f, 0.f, 0.f}, e01 = e00, e10 = e00, e11 = e00;
      const _Float16* w2a = g_w2 + ((size_t)wid * KT2) * 512 + lane * 8;
      const _Float16* w2b = g_w2 + ((size_t)(16 + wid) * KT2) * 512 + lane * 8;
      const int ab = lane * 8;
      f16x8 ba0 = *(const f16x8*)(w2a);
      f16x8 bb0 = (wid < 4) ? *(const f16x8*)(w2b) : f16x8_zero();
      f16x8 ba1 = *(const f16x8*)(w2a + 512);
      f16x8 bb1 = (wid < 4) ? *(const f16x8*)(w2b + 512) : f16x8_zero();
      f16x8 cah0 = *(const f16x8*)&sAhi[15 * 1024 + ab];
      f16x8 cal0 = *(const f16x8*)&sAlo[15 * 1024 + ab];
      f16x8 cah1 = *(const f16x8*)&sAhi[15 * 1024 + ab + 512];
      f16x8 cal1 = *(const f16x8*)&sAlo[15 * 1024 + ab + 512];
#pragma unroll
      for (int qt = 0; qt < KT2; ++qt) {
        f16x8 nah0, nal0, nah1, nal1, ba2, bb2;
        if (qt + 1 < KT2) {
          const int o2 = (16 + qt) * 1024 + ab;
          nah0 = *(const f16x8*)&sAhi[o2];
          nal0 = *(const f16x8*)&sAlo[o2];
          nah1 = *(const f16x8*)&sAhi[o2 + 512];
          nal1 = *(const f16x8*)&sAlo[o2 + 512];
        }
        if (qt + 2 < KT2) {
          ba2 = *(const f16x8*)(w2a + (qt + 2) * 512);
          if (wid < 4) bb2 = *(const f16x8*)(w2b + (qt + 2) * 512);
        }
        SBAR();
        e00 = MFMA16(cah0, ba0, e00); e00 = MFMA16(cal0, ba0, e00);
        e01 = MFMA16(cah1, ba0, e01); e01 = MFMA16(cal1, ba0, e01);
        if (wid < 4) {
          e10 = MFMA16(cah0, bb0, e10); e10 = MFMA16(cal0, bb0, e10);
          e11 = MFMA16(cah1, bb0, e11); e11 = MFMA16(cal1, bb0, e11);
        }
        if (qt + 1 < KT2) { cah0 = nah0; cal0 = nal0; cah1 = nah1; cal1 = nal1; }
        ba0 = ba1; bb0 = bb1;
        if (qt + 2 < KT2) { ba1 = ba2; if (wid < 4) bb1 = bb2; }
      }
      ASTORE(e00, e01, wid * 16)                       // cols < 256
      if (wid < 4) ASTORE(e10, e11, (16 + wid) * 16)   // cols 256..319
#undef ASTORE
    }
    __syncthreads();

    // ========== phase F: KG partials (4 waves, k-halves, pinned) ==========
    if (wid < 4) {
      const int mB = wid & 1, half = wid >> 1;
      f32x4 ka = {0.f, 0.f, 0.f, 0.f};
      const _Float16* w3p = g_w3 + lane * 8;
      f16x8 bwC = *(const f16x8*)(w3p + (half * 5) * 512);
#pragma unroll
      for (int q = 0; q < 5; ++q) {
        const int kt3 = half * 5 + q;
        f16x8 bwN;
        if (q + 1 < 5) bwN = *(const f16x8*)(w3p + (kt3 + 1) * 512);
        const int _o = (kt3 * 2 + mB) * 512 + lane * 8;
        const f16x8 ah = *(const f16x8*)&sAhi[_o];
        const f16x8 al = *(const f16x8*)&sAlo[_o];
        SBAR();
        ka = MFMA16(ah, bwC, ka); ka = MFMA16(al, bwC, ka);
        if (q + 1 < 5) bwC = bwN;
      }
      const int c = lane & 15;
      if (c < 8) {
        const int rb = mB * 16 + g4;
#pragma unroll
        for (int reg = 0; reg < 4; ++reg) s_kgp[half][rb + reg][c] = ka[reg];
      }
    }
    __syncthreads();
  }

  // ---- final F2 (t = 31) ----
  {
    float kg[8];
#pragma unroll
    for (int cc = 0; cc < 8; ++cc)
      kg[cc] = s_kgp[0][rl][cc] + s_kgp[1][rl][cc] + s_b3[cc];
#pragma unroll
    for (int m = 0; m < 4; ++m)
      post[m] = prior[m] + kg[2 * m] * d0 + kg[2 * m + 1] * d1;
    if (wid == 0 && lane < 32) {
      float4 o; o.x = post[0]; o.y = post[1]; o.z = post[2]; o.w = post[3];
      *(float4*)&out[((size_t)(T_STEPS - 1) * BATCH + row0 + rl) * 4] = o;
    }
  }
}

}  // namespace

extern "C" void kernel_launch(void* const* d_in, const int* in_sizes, int n_in,
                              void* d_out, int out_size, void* d_ws, size_t ws_size,
                              hipStream_t stream) {
  const float* y   = (const float*)d_in[0];
  const float* Fm  = (const float*)d_in[1];
  const float* Hm  = (const float*)d_in[2];
  const float* W1  = (const float*)d_in[3];
  const float* b1  = (const float*)d_in[4];
  const float* Wg  = (const float*)d_in[5];
  const float* Ug  = (const float*)d_in[6];
  const float* bg  = (const float*)d_in[7];
  const float* W2  = (const float*)d_in[8];
  const float* b2  = (const float*)d_in[9];
  const float* W3  = (const float*)d_in[10];
  const float* b3  = (const float*)d_in[11];
  const float* hn0 = (const float*)d_in[12];
  float* out = (float*)d_out;

  constexpr int PREP_TOT = (NTW1 + NTG * KTG + NT2 * KT2 + KT3) * 512;
  prep_kernel<<<(PREP_TOT + 255) / 256, 256, 0, stream>>>(W1, b1, Wg, Ug, W2, b2, W3);
  knet_kernel<<<BATCH / BR, NTHR, 0, stream>>>(y, Fm, Hm, bg, b3, hn0, out);
}

// Round 7
// 1407.433 us; speedup vs baseline: 2.9238x; 1.0713x over previous
//
#include <hip/hip_runtime.h>

// KalmanNet recurrent step, MFMA fp16, r7: spill-free register budget.
//
// r6 post-mortem: VGPR_Count=64 is the ARCH half of the unified file (acc
// f32x4[8] lives in the AGPR half); r6's depth-2 B prefetch + A dbuf needed
// ~90 arch regs => forced spills (WRITE_SIZE 329 MB vs 4 MB real output),
// whose scratch stream thrashed per-XCD L2 and evicted the 1.3 MB weight
// set (FETCH 2.4 GB vs ~25 MB compulsory). r7 shrinks the pinned pipeline
// to fit 64 arch regs: A fragments read AT USE (no dbuf), B prefetch
// depth-1, issue order still pinned with sched_barrier(0). Live set ~55.
// Once spills die, weights stay L2-resident and depth-1 (~1 MFMA cluster
// of cover) matches the restored ~200-300cyc L2 latency.
//
// Structure (unchanged from r5/r6): 32 rows/block, T=32 recurrence
// in-kernel, 1024 threads (16 waves, 4/SIMD). GEMMs on
// v_mfma_f32_16x16x32_f16, A split hi/lo fp16 (exact activations; only
// fp16 weight quantization error). Weights prepacked to fragment order
// (~1.2 MB). Gates GEMM: 52 real j-tiles (13/group z|r|xh|hh), wave w<13
// owns j-tile w of each group; per kt: 3 B loads, 12 MFMAs; xh kt 0..14 /
// hh kt 15..21 (k-disjoint, tile-aligned). GRU update in registers; h
// lives in A-fragment slots k=480+j. Bias folding: W1 ones-row k=8 -> b1;
// h-pad k=680 == 1.0 carries b2 via g_w2 row 200.
//
// Fragment maps (verified r2-r6): A/B k = kt*32 + (lane>>4)*8 + i,
// A row / B col = lane&15; C/D col = lane&15, row = (lane>>4)*4 + reg.

namespace {

constexpr int T_STEPS = 32;
constexpr int BATCH   = 8192;
constexpr int H1      = 480;
constexpr int HID     = 200;
constexpr int H2      = 320;
constexpr int BR      = 32;    // batch rows per block (2 MFMA m-tiles)
constexpr int NTHR    = 1024;  // 16 waves
constexpr int KTG     = 22;    // gates K tiles (704 = 480 a1 + 224 h/pad)
constexpr int NTG     = 52;    // 4 groups x 13 real j-tiles
constexpr int NTW1    = 32;    // W1 col tiles
constexpr int NT2     = 20;    // W2 real col tiles (320/16)
constexpr int KT2     = 7;     // W2 K tiles (224)
constexpr int KT3     = 10;    // W3 K tiles (320)

using f16x8 = __attribute__((ext_vector_type(8))) _Float16;
using f32x4 = __attribute__((ext_vector_type(4))) float;

__device__ _Float16 g_w1[NTW1 * 512];          // [nt][lane][8], k=8 row = b1
__device__ _Float16 g_wcat[NTG * KTG * 512];   // [grp*13+tile][kt][lane][8]
__device__ _Float16 g_w2[NT2 * KT2 * 512];     // [nt][kt][lane][8], k_h=200 = b2
__device__ _Float16 g_w3[KT3 * 512];           // [kt][lane][8], cols 8..15 = 0

#define MFMA16(A, B, C) __builtin_amdgcn_mfma_f32_16x16x32_f16((A), (B), (C), 0, 0, 0)
#define SBAR() __builtin_amdgcn_sched_barrier(0)

__device__ __forceinline__ float sigmoid_(float x) { return 1.f / (1.f + __expf(-x)); }
__device__ __forceinline__ float tanh_(float x) {
  x = fminf(fmaxf(x, -15.f), 15.f);
  const float e = __expf(-2.f * x);
  return (1.f - e) / (1.f + e);
}
__device__ __forceinline__ f16x8 f16x8_zero() {
  f16x8 v;
#pragma unroll
  for (int i = 0; i < 8; ++i) v[i] = (_Float16)0.f;
  return v;
}

// element (k, r) -> flat half index in A-fragment LDS layout
// [kt][m=r>>4][lane=((k&31)>>3)*16 + (r&15)][i=k&7]
__device__ __forceinline__ int afrag_off(int k, int r) {
  const int kt = k >> 5, kk = k & 31;
  return ((kt * 2 + (r >> 4)) * 512) + ((((kk >> 3) << 4) | (r & 15)) * 8) + (kk & 7);
}

// ---------------- weight pre-pack ----------------
__global__ __launch_bounds__(256) void prep_kernel(
    const float* __restrict__ W1, const float* __restrict__ b1,
    const float* __restrict__ Wg, const float* __restrict__ Ug,
    const float* __restrict__ W2, const float* __restrict__ b2,
    const float* __restrict__ W3) {
  const int idx = blockIdx.x * 256 + threadIdx.x;
  constexpr int TOTW1 = NTW1 * 512;
  constexpr int TOT1  = NTG * KTG * 512;
  constexpr int TOT2  = NT2 * KT2 * 512;
  constexpr int TOT3  = KT3 * 512;
  if (idx < TOTW1) {
    const int i = idx & 7, l = (idx >> 3) & 63, nt = idx >> 9;
    const int g = l >> 4, c = l & 15;
    const int k = g * 8 + i, col = nt * 16 + c;
    float wv = 0.f;
    if (col < H1) {
      if (k < 8) wv = W1[k * H1 + col];
      else if (k == 8) wv = b1[col];
    }
    g_w1[idx] = (_Float16)wv;
  } else if (idx < TOTW1 + TOT1) {
    const int id = idx - TOTW1;
    const int i = id & 7, l = (id >> 3) & 63, nk = id >> 9;
    const int kt = nk % KTG, nt = nk / KTG;
    const int g = l >> 4, c = l & 15;
    const int k = kt * 32 + g * 8 + i;        // 0..703
    const int grp = nt / 13;                  // 0=z 1=r 2=xh 3=hh
    const int jj = (nt - grp * 13) * 16 + c;  // 0..207
    float wv = 0.f;
    if (jj < HID) {
      if (grp == 0) {
        if (k < H1) wv = Wg[k * 600 + jj];
        else if (k < H1 + HID) wv = Ug[(k - H1) * 600 + jj];
      } else if (grp == 1) {
        if (k < H1) wv = Wg[k * 600 + 200 + jj];
        else if (k < H1 + HID) wv = Ug[(k - H1) * 600 + 200 + jj];
      } else if (grp == 2) {
        if (k < H1) wv = Wg[k * 600 + 400 + jj];           // xh: a1 rows only
      } else {
        if (k >= H1 && k < H1 + HID) wv = Ug[(k - H1) * 600 + 400 + jj];  // hh
      }
    }
    g_wcat[id] = (_Float16)wv;
  } else if (idx < TOTW1 + TOT1 + TOT2) {
    const int id = idx - TOTW1 - TOT1;
    const int i = id & 7, l = (id >> 3) & 63, nk = id >> 9;
    const int kt = nk % KT2, nt = nk / KT2;
    const int g = l >> 4, c = l & 15;
    const int k = kt * 32 + g * 8 + i;        // 0..223
    const int col = nt * 16 + c;              // 0..319 (all real)
    float wv = 0.f;
    if (k < HID) wv = W2[k * H2 + col];
    else if (k == 200) wv = b2[col];          // ones-row at k_h=200 (k=680)
    g_w2[id] = (_Float16)wv;
  } else if (idx < TOTW1 + TOT1 + TOT2 + TOT3) {
    const int id = idx - TOTW1 - TOT1 - TOT2;
    const int i = id & 7, l = (id >> 3) & 63, kt = id >> 9;
    const int g = l >> 4, c = l & 15;
    const int k = kt * 32 + g * 8 + i;        // 0..319
    g_w3[id] = (_Float16)((c < 8) ? W3[k * 8 + c] : 0.f);
  }
}

// ---------------- main recurrent kernel ----------------
__global__
__attribute__((amdgpu_flat_work_group_size(NTHR, NTHR)))
__attribute__((amdgpu_waves_per_eu(4, 4)))
void knet_kernel(
    const float* __restrict__ y,    // [T,B,2]
    const float* __restrict__ Fm,   // [4,4]
    const float* __restrict__ Hm,   // [2,4]
    const float* __restrict__ bg,   // [2,600]
    const float* __restrict__ b3,   // [8]
    const float* __restrict__ hn0,  // [B,200]
    float* __restrict__ out)        // [T,B,4]
{
  // A-fragments of x_cat = [a1(480) | h(200) | 1.0 @680 | 0-pad]; a2 reuses
  // slots 0..9 between phase E and phase F.
  __shared__ alignas(16) _Float16 sAhi[KTG * 2 * 512];   // 45056 B
  __shared__ alignas(16) _Float16 sAlo[KTG * 2 * 512];   // 45056 B
  __shared__ alignas(16) float s_in8T[8][BR];
  __shared__ alignas(16) float s_kgp[2][BR][8];          // KG k-half partials
  __shared__ alignas(16) float s_bias[4][HID];
  __shared__ alignas(16) float s_fh[32];                 // Fm[16], Hm[8]
  __shared__ alignas(16) float s_b3[8];

  const int tid  = threadIdx.x;
  const int lane = tid & 63;
  const int wid  = __builtin_amdgcn_readfirstlane(tid >> 6);  // 0..15
  const int row0 = blockIdx.x * BR;
  const int rl   = lane & 31;
  const int g4   = (lane >> 4) << 2;

  // ---- init ----
  if (tid < HID) {
    s_bias[0][tid] = bg[tid]       + bg[600 + tid];   // z
    s_bias[1][tid] = bg[200 + tid] + bg[800 + tid];   // r
    s_bias[2][tid] = bg[400 + tid];                   // xh (input bias)
    s_bias[3][tid] = bg[1000 + tid];                  // hh (recurrent bias)
  }
  if (tid < 16) s_fh[tid] = Fm[tid];
  else if (tid < 24) s_fh[tid] = Hm[tid - 16];
  if (tid < 8) s_b3[tid] = b3[tid];
  for (int e = tid; e < HID * BR; e += NTHR) {
    const int j = e >> 5, r = e & 31;
    const float h0 = hn0[(size_t)(row0 + r) * HID + j];
    const int off = afrag_off(480 + j, r);
    const _Float16 hi = (_Float16)h0;
    sAhi[off] = hi;
    sAlo[off] = (_Float16)(h0 - (float)hi);
  }
  for (int e = tid; e < 24 * BR; e += NTHR) {   // k 680..703: 1.0 then zeros
    const int k = 680 + (e >> 5), r = e & 31;
    const int off = afrag_off(k, r);
    sAhi[off] = (_Float16)((k == 680) ? 1.f : 0.f);
    sAlo[off] = (_Float16)0.f;
  }
  __syncthreads();

  // persistent per-lane state (row rl)
  float prior[4] = {0.f, 0.f, 0.f, 0.f};
  float post[4]  = {0.f, 0.f, 0.f, 0.f};
  float d0 = 0.f, d1 = 0.f;

  for (int t = 0; t < T_STEPS; ++t) {
    // ================= phase 1: F2(t-1) + A(t) + W1-GEMM(t) =================
    if (t > 0) {
      float kg[8];
#pragma unroll
      for (int cc = 0; cc < 8; ++cc)
        kg[cc] = s_kgp[0][rl][cc] + s_kgp[1][rl][cc] + s_b3[cc];
#pragma unroll
      for (int m = 0; m < 4; ++m)
        post[m] = prior[m] + kg[2 * m] * d0 + kg[2 * m + 1] * d1;
      if (wid == 0 && lane < 32) {
        float4 o; o.x = post[0]; o.y = post[1]; o.z = post[2]; o.w = post[3];
        *(float4*)&out[((size_t)(t - 1) * BATCH + row0 + rl) * 4] = o;
      }
    }
    {   // ---- A: prior / innovation / features (redundant per wave) ----
      float opri[4], np[4];
#pragma unroll
      for (int m = 0; m < 4; ++m) opri[m] = prior[m];
#pragma unroll
      for (int m = 0; m < 4; ++m) {
        float s = 0.f;
#pragma unroll
        for (int j = 0; j < 4; ++j) s += s_fh[m * 4 + j] * post[j];
        np[m] = s;
      }
      float m0 = 0.f, m1 = 0.f;
#pragma unroll
      for (int m = 0; m < 4; ++m) { m0 += s_fh[16 + m] * np[m]; m1 += s_fh[20 + m] * np[m]; }
      const float2 yv = *(const float2*)&y[((size_t)t * BATCH + row0 + rl) * 2];
      d0 = yv.x - m0;
      d1 = yv.y - m1;
      float dx[4], ssx = 0.f;
#pragma unroll
      for (int m = 0; m < 4; ++m) { dx[m] = post[m] - opri[m]; ssx += dx[m] * dx[m]; }
      const float idx_ = rsqrtf(fmaxf(ssx, 1e-12f));
      const float idy_ = rsqrtf(fmaxf(d0 * d0 + d1 * d1, 1e-12f));
#pragma unroll
      for (int m = 0; m < 4; ++m) prior[m] = np[m];
      if (lane < 32) {
        const float n0 = d0 * idy_, n1 = d1 * idy_;
        s_in8T[0][rl] = n0; s_in8T[1][rl] = n1;
        s_in8T[2][rl] = n0; s_in8T[3][rl] = n1;
#pragma unroll
        for (int m = 0; m < 4; ++m) s_in8T[4 + m][rl] = dx[m] * idx_;
      }
    }
    {   // ---- W1-GEMM: a1 = relu([in8,1] @ [W1;b1]), 2 tiles/wave ----
      f16x8 ah0 = f16x8_zero(), al0 = f16x8_zero();
      f16x8 ah1 = f16x8_zero(), al1 = f16x8_zero();
      const int g = lane >> 4, c = lane & 15;
      if (g == 0) {
#pragma unroll
        for (int i = 0; i < 8; ++i) {
          const float v0 = s_in8T[i][c];
          const float v1 = s_in8T[i][c + 16];
          const _Float16 h0 = (_Float16)v0; ah0[i] = h0; al0[i] = (_Float16)(v0 - (float)h0);
          const _Float16 h1 = (_Float16)v1; ah1[i] = h1; al1[i] = (_Float16)(v1 - (float)h1);
        }
      } else if (g == 1) {
        ah0[0] = (_Float16)1.f;   // ones-row k=8 -> b1
        ah1[0] = (_Float16)1.f;
      }
      f32x4 p00 = {0.f, 0.f, 0.f, 0.f}, p01 = p00, p10 = p00, p11 = p00;
      const f16x8 w1a = *(const f16x8*)&g_w1[(size_t)wid * 512 + lane * 8];
      const f16x8 w1b = *(const f16x8*)&g_w1[(size_t)(16 + wid) * 512 + lane * 8];
      p00 = MFMA16(ah0, w1a, p00); p00 = MFMA16(al0, w1a, p00);
      p01 = MFMA16(ah1, w1a, p01); p01 = MFMA16(al1, w1a, p01);
      p10 = MFMA16(ah0, w1b, p10); p10 = MFMA16(al0, w1b, p10);
      p11 = MFMA16(ah1, w1b, p11); p11 = MFMA16(al1, w1b, p11);
#define ASTORE(A0, A1, COLBASE)                                      \
      { const int col = (COLBASE) + (lane & 15);                     \
        _Pragma("unroll")                                            \
        for (int reg = 0; reg < 4; ++reg) {                          \
          const float v0 = fmaxf(A0[reg], 0.f);                      \
          const float v1 = fmaxf(A1[reg], 0.f);                      \
          const int o0 = afrag_off(col, g4 + reg);                   \
          const int o1 = afrag_off(col, 16 + g4 + reg);              \
          const _Float16 q0 = (_Float16)v0, q1 = (_Float16)v1;       \
          sAhi[o0] = q0; sAlo[o0] = (_Float16)(v0 - (float)q0);      \
          sAhi[o1] = q1; sAlo[o1] = (_Float16)(v1 - (float)q1);      \
        } }
      ASTORE(p00, p01, wid * 16)
      if (wid < 14) ASTORE(p10, p11, (16 + wid) * 16)
    }
    __syncthreads();

    // == phase C: gates GEMM (waves 0..12; A at use, B depth-1, pinned) ==
    f32x4 aZ0 = {0.f, 0.f, 0.f, 0.f}, aZ1 = aZ0, aR0 = aZ0, aR1 = aZ0;
    f32x4 aX0 = aZ0, aX1 = aZ0, aH0 = aZ0, aH1 = aZ0;
    if (wid < 13) {
      const _Float16* bzp = g_wcat + ((size_t)(0  + wid) * KTG) * 512 + lane * 8;
      const _Float16* brp = g_wcat + ((size_t)(13 + wid) * KTG) * 512 + lane * 8;
      const _Float16* bxp = g_wcat + ((size_t)(26 + wid) * KTG) * 512 + lane * 8;
      const _Float16* bhp = g_wcat + ((size_t)(39 + wid) * KTG) * 512 + lane * 8;
#define LD3(KT) (((KT) < 15) ? *(const f16x8*)(bxp + (KT) * 512) \
                             : *(const f16x8*)(bhp + (KT) * 512))
      const int ab = lane * 8;
      f16x8 bzC = *(const f16x8*)(bzp);
      f16x8 brC = *(const f16x8*)(brp);
      f16x8 bxC = LD3(0);
#pragma unroll
      for (int kt = 0; kt < KTG; ++kt) {
        // A(kt) LDS reads at use
        const int _o = kt * 1024 + ab;
        const f16x8 cah0 = *(const f16x8*)&sAhi[_o];
        const f16x8 cal0 = *(const f16x8*)&sAlo[_o];
        const f16x8 cah1 = *(const f16x8*)&sAhi[_o + 512];
        const f16x8 cal1 = *(const f16x8*)&sAlo[_o + 512];
        // B(kt+1) global loads, issued before kt's MFMA cluster
        f16x8 bzN, brN, bxN;
        if (kt + 1 < KTG) {
          bzN = *(const f16x8*)(bzp + (kt + 1) * 512);
          brN = *(const f16x8*)(brp + (kt + 1) * 512);
          bxN = LD3(kt + 1);
        }
        SBAR();                         // pin: loads issue BEFORE kt's MFMAs
        aZ0 = MFMA16(cah0, bzC, aZ0);  aZ0 = MFMA16(cal0, bzC, aZ0);
        aZ1 = MFMA16(cah1, bzC, aZ1);  aZ1 = MFMA16(cal1, bzC, aZ1);
        aR0 = MFMA16(cah0, brC, aR0);  aR0 = MFMA16(cal0, brC, aR0);
        aR1 = MFMA16(cah1, brC, aR1);  aR1 = MFMA16(cal1, brC, aR1);
        if (kt < 15) {
          aX0 = MFMA16(cah0, bxC, aX0); aX0 = MFMA16(cal0, bxC, aX0);
          aX1 = MFMA16(cah1, bxC, aX1); aX1 = MFMA16(cal1, bxC, aX1);
        } else {
          aH0 = MFMA16(cah0, bxC, aH0); aH0 = MFMA16(cal0, bxC, aH0);
          aH1 = MFMA16(cah1, bxC, aH1); aH1 = MFMA16(cal1, bxC, aH1);
        }
        if (kt + 1 < KTG) { bzC = bzN; brC = brN; bxC = bxN; }
      }
#undef LD3
    }
    __syncthreads();   // all h reads done before in-place h update

    // ================= phase D': in-register GRU update =================
    if (wid < 13) {
      const int c = lane & 15;
      const int j = wid * 16 + c;
      if (j < HID) {
        const float bz  = s_bias[0][j], brb = s_bias[1][j];
        const float bxh = s_bias[2][j], bhh = s_bias[3][j];
#define GRU1(AZ, AR, AX, AH, MB)                                         \
        _Pragma("unroll")                                                \
        for (int reg = 0; reg < 4; ++reg) {                              \
          const int r = (MB) * 16 + g4 + reg;                            \
          const int off = afrag_off(480 + j, r);                         \
          const float hold = (float)sAhi[off] + (float)sAlo[off];        \
          const float z  = sigmoid_(AZ[reg] + bz);                       \
          const float rr = sigmoid_(AR[reg] + brb);                      \
          const float hc = tanh_((AX[reg] + bxh) + rr * (AH[reg] + bhh));\
          const float hn = z * hold + (1.f - z) * hc;                    \
          const _Float16 qh = (_Float16)hn;                              \
          sAhi[off] = qh;                                                \
          sAlo[off] = (_Float16)(hn - (float)qh);                       \
        }
        GRU1(aZ0, aR0, aX0, aH0, 0)
        GRU1(aZ1, aR1, aX1, aH1, 1)
#undef GRU1
      }
    }
    __syncthreads();

    // == phase E: a2 = relu(h @ W2 + b2); A at use, B depth-1, pinned ==
    {
      f32x4 e00 = {0.f, 0.f, 0.f, 0.f}, e01 = e00, e10 = e00, e11 = e00;
      const _Float16* w2a = g_w2 + ((size_t)wid * KT2) * 512 + lane * 8;
      const _Float16* w2b = g_w2 + ((size_t)(16 + wid) * KT2) * 512 + lane * 8;
      const int ab = lane * 8;
      f16x8 baC = *(const f16x8*)(w2a);
      f16x8 bbC = (wid < 4) ? *(const f16x8*)(w2b) : f16x8_zero();
#pragma unroll
      for (int qt = 0; qt < KT2; ++qt) {
        const int _o = (15 + qt) * 1024 + ab;
        const f16x8 cah0 = *(const f16x8*)&sAhi[_o];
        const f16x8 cal0 = *(const f16x8*)&sAlo[_o];
        const f16x8 cah1 = *(const f16x8*)&sAhi[_o + 512];
        const f16x8 cal1 = *(const f16x8*)&sAlo[_o + 512];
        f16x8 baN, bbN;
        if (qt + 1 < KT2) {
          baN = *(const f16x8*)(w2a + (qt + 1) * 512);
          if (wid < 4) bbN = *(const f16x8*)(w2b + (qt + 1) * 512);
        }
        SBAR();
        e00 = MFMA16(cah0, baC, e00); e00 = MFMA16(cal0, baC, e00);
        e01 = MFMA16(cah1, baC, e01); e01 = MFMA16(cal1, baC, e01);
        if (wid < 4) {
          e10 = MFMA16(cah0, bbC, e10); e10 = MFMA16(cal0, bbC, e10);
          e11 = MFMA16(cah1, bbC, e11); e11 = MFMA16(cal1, bbC, e11);
        }
        if (qt + 1 < KT2) { baC = baN; if (wid < 4) bbC = bbN; }
      }
      ASTORE(e00, e01, wid * 16)                       // cols < 256
      if (wid < 4) ASTORE(e10, e11, (16 + wid) * 16)   // cols 256..319
#undef ASTORE
    }
    __syncthreads();

    // ========== phase F: KG partials (4 waves, k-halves, pinned) ==========
    if (wid < 4) {
      const int mB = wid & 1, half = wid >> 1;
      f32x4 ka = {0.f, 0.f, 0.f, 0.f};
      const _Float16* w3p = g_w3 + lane * 8;
      f16x8 bwC = *(const f16x8*)(w3p + (half * 5) * 512);
#pragma unroll
      for (int q = 0; q < 5; ++q) {
        const int kt3 = half * 5 + q;
        f16x8 bwN;
        if (q + 1 < 5) bwN = *(const f16x8*)(w3p + (kt3 + 1) * 512);
        const int _o = (kt3 * 2 + mB) * 512 + lane * 8;
        const f16x8 ah = *(const f16x8*)&sAhi[_o];
        const f16x8 al = *(const f16x8*)&sAlo[_o];
        SBAR();
        ka = MFMA16(ah, bwC, ka); ka = MFMA16(al, bwC, ka);
        if (q + 1 < 5) bwC = bwN;
      }
      const int c = lane & 15;
      if (c < 8) {
        const int rb = mB * 16 + g4;
#pragma unroll
        for (int reg = 0; reg < 4; ++reg) s_kgp[half][rb + reg][c] = ka[reg];
      }
    }
    __syncthreads();
  }

  // ---- final F2 (t = 31) ----
  {
    float kg[8];
#pragma unroll
    for (int cc = 0; cc < 8; ++cc)
      kg[cc] = s_kgp[0][rl][cc] + s_kgp[1][rl][cc] + s_b3[cc];
#pragma unroll
    for (int m = 0; m < 4; ++m)
      post[m] = prior[m] + kg[2 * m] * d0 + kg[2 * m + 1] * d1;
    if (wid == 0 && lane < 32) {
      float4 o; o.x = post[0]; o.y = post[1]; o.z = post[2]; o.w = post[3];
      *(float4*)&out[((size_t)(T_STEPS - 1) * BATCH + row0 + rl) * 4] = o;
    }
  }
}

}  // namespace

extern "C" void kernel_launch(void* const* d_in, const int* in_sizes, int n_in,
                              void* d_out, int out_size, void* d_ws, size_t ws_size,
                              hipStream_t stream) {
  const float* y   = (const float*)d_in[0];
  const float* Fm  = (const float*)d_in[1];
  const float* Hm  = (const float*)d_in[2];
  const float* W1  = (const float*)d_in[3];
  const float* b1  = (const float*)d_in[4];
  const float* Wg  = (const float*)d_in[5];
  const float* Ug  = (const float*)d_in[6];
  const float* bg  = (const float*)d_in[7];
  const float* W2  = (const float*)d_in[8];
  const float* b2  = (const float*)d_in[9];
  const float* W3  = (const float*)d_in[10];
  const float* b3  = (const float*)d_in[11];
  const float* hn0 = (const float*)d_in[12];
  float* out = (float*)d_out;

  constexpr int PREP_TOT = (NTW1 + NTG * KTG + NT2 * KT2 + KT3) * 512;
  prep_kernel<<<(PREP_TOT + 255) / 256, 256, 0, stream>>>(W1, b1, Wg, Ug, W2, b2, W3);
  knet_kernel<<<BATCH / BR, NTHR, 0, stream>>>(y, Fm, Hm, bg, b3, hn0, out);
}

// Round 8
// 1365.289 us; speedup vs baseline: 3.0140x; 1.0309x over previous
//
#include <hip/hip_runtime.h>

// KalmanNet recurrent step, MFMA fp16, r8: persistent state -> LDS (kill spills).
//
// r7 post-mortem: WRITE_SIZE still 283 MB = 34 B/thread/step = exactly the 10
// persistent floats (prior[4], post[4], d0, d1) that live across every barrier
// of the t-loop. With 64 arch VGPRs (other 64 of the unified budget = the 8
// f32x4 accumulators), the allocator spills precisely the longest-lived regs.
// The scratch stream (~500 GB/s R+W) thrashes each XCD's 4 MB L2 (scratch
// ~1.3 MB/XCD + weights 1.25 MB), evicting the weight set -> FETCH 2.1 GB and
// HBM-latency B misses that depth-1 prefetch can't cover.
//
// r8: state moves to double-buffered LDS (s_prior2[2], s_d2[2], parity t&1:
// read p, write p^1; all cross-step reuse barrier-separated; identical-value
// multi-wave writes, same pattern as s_in8T). Zero cross-barrier VGPRs.
//
// Structure otherwise = r7: 32 rows/block, T=32 in-kernel, 1024 thr (16
// waves, 4/SIMD). v_mfma_f32_16x16x32_f16, A hi/lo fp16 split (exact
// activations; only fp16 weight quant error). Weights prepacked (~1.2 MB).
// Gates GEMM: 52 real j-tiles (13/group z|r|xh|hh), wave w<13 owns j-tile w
// of each group; 3 B loads + 12 MFMAs per kt; xh kt<15 / hh kt>=15. GRU in
// registers; h lives in A-fragment slots k=480+j. Bias folding: W1 ones-row
// k=8 -> b1; h-pad k=680==1.0 carries b2 via g_w2 row 200.
//
// Fragment maps (verified r2-r7): A/B k = kt*32 + (lane>>4)*8 + i,
// A row / B col = lane&15; C/D col = lane&15, row = (lane>>4)*4 + reg.

namespace {

constexpr int T_STEPS = 32;
constexpr int BATCH   = 8192;
constexpr int H1      = 480;
constexpr int HID     = 200;
constexpr int H2      = 320;
constexpr int BR      = 32;    // batch rows per block (2 MFMA m-tiles)
constexpr int NTHR    = 1024;  // 16 waves
constexpr int KTG     = 22;    // gates K tiles (704 = 480 a1 + 224 h/pad)
constexpr int NTG     = 52;    // 4 groups x 13 real j-tiles
constexpr int NTW1    = 32;    // W1 col tiles
constexpr int NT2     = 20;    // W2 real col tiles (320/16)
constexpr int KT2     = 7;     // W2 K tiles (224)
constexpr int KT3     = 10;    // W3 K tiles (320)

using f16x8 = __attribute__((ext_vector_type(8))) _Float16;
using f32x4 = __attribute__((ext_vector_type(4))) float;

__device__ _Float16 g_w1[NTW1 * 512];          // [nt][lane][8], k=8 row = b1
__device__ _Float16 g_wcat[NTG * KTG * 512];   // [grp*13+tile][kt][lane][8]
__device__ _Float16 g_w2[NT2 * KT2 * 512];     // [nt][kt][lane][8], k_h=200 = b2
__device__ _Float16 g_w3[KT3 * 512];           // [kt][lane][8], cols 8..15 = 0

#define MFMA16(A, B, C) __builtin_amdgcn_mfma_f32_16x16x32_f16((A), (B), (C), 0, 0, 0)
#define SBAR() __builtin_amdgcn_sched_barrier(0)

__device__ __forceinline__ float sigmoid_(float x) { return 1.f / (1.f + __expf(-x)); }
__device__ __forceinline__ float tanh_(float x) {
  x = fminf(fmaxf(x, -15.f), 15.f);
  const float e = __expf(-2.f * x);
  return (1.f - e) / (1.f + e);
}
__device__ __forceinline__ f16x8 f16x8_zero() {
  f16x8 v;
#pragma unroll
  for (int i = 0; i < 8; ++i) v[i] = (_Float16)0.f;
  return v;
}

// element (k, r) -> flat half index in A-fragment LDS layout
// [kt][m=r>>4][lane=((k&31)>>3)*16 + (r&15)][i=k&7]
__device__ __forceinline__ int afrag_off(int k, int r) {
  const int kt = k >> 5, kk = k & 31;
  return ((kt * 2 + (r >> 4)) * 512) + ((((kk >> 3) << 4) | (r & 15)) * 8) + (kk & 7);
}

// ---------------- weight pre-pack ----------------
__global__ __launch_bounds__(256) void prep_kernel(
    const float* __restrict__ W1, const float* __restrict__ b1,
    const float* __restrict__ Wg, const float* __restrict__ Ug,
    const float* __restrict__ W2, const float* __restrict__ b2,
    const float* __restrict__ W3) {
  const int idx = blockIdx.x * 256 + threadIdx.x;
  constexpr int TOTW1 = NTW1 * 512;
  constexpr int TOT1  = NTG * KTG * 512;
  constexpr int TOT2  = NT2 * KT2 * 512;
  constexpr int TOT3  = KT3 * 512;
  if (idx < TOTW1) {
    const int i = idx & 7, l = (idx >> 3) & 63, nt = idx >> 9;
    const int g = l >> 4, c = l & 15;
    const int k = g * 8 + i, col = nt * 16 + c;
    float wv = 0.f;
    if (col < H1) {
      if (k < 8) wv = W1[k * H1 + col];
      else if (k == 8) wv = b1[col];
    }
    g_w1[idx] = (_Float16)wv;
  } else if (idx < TOTW1 + TOT1) {
    const int id = idx - TOTW1;
    const int i = id & 7, l = (id >> 3) & 63, nk = id >> 9;
    const int kt = nk % KTG, nt = nk / KTG;
    const int g = l >> 4, c = l & 15;
    const int k = kt * 32 + g * 8 + i;        // 0..703
    const int grp = nt / 13;                  // 0=z 1=r 2=xh 3=hh
    const int jj = (nt - grp * 13) * 16 + c;  // 0..207
    float wv = 0.f;
    if (jj < HID) {
      if (grp == 0) {
        if (k < H1) wv = Wg[k * 600 + jj];
        else if (k < H1 + HID) wv = Ug[(k - H1) * 600 + jj];
      } else if (grp == 1) {
        if (k < H1) wv = Wg[k * 600 + 200 + jj];
        else if (k < H1 + HID) wv = Ug[(k - H1) * 600 + 200 + jj];
      } else if (grp == 2) {
        if (k < H1) wv = Wg[k * 600 + 400 + jj];           // xh: a1 rows only
      } else {
        if (k >= H1 && k < H1 + HID) wv = Ug[(k - H1) * 600 + 400 + jj];  // hh
      }
    }
    g_wcat[id] = (_Float16)wv;
  } else if (idx < TOTW1 + TOT1 + TOT2) {
    const int id = idx - TOTW1 - TOT1;
    const int i = id & 7, l = (id >> 3) & 63, nk = id >> 9;
    const int kt = nk % KT2, nt = nk / KT2;
    const int g = l >> 4, c = l & 15;
    const int k = kt * 32 + g * 8 + i;        // 0..223
    const int col = nt * 16 + c;              // 0..319 (all real)
    float wv = 0.f;
    if (k < HID) wv = W2[k * H2 + col];
    else if (k == 200) wv = b2[col];          // ones-row at k_h=200 (k=680)
    g_w2[id] = (_Float16)wv;
  } else if (idx < TOTW1 + TOT1 + TOT2 + TOT3) {
    const int id = idx - TOTW1 - TOT1 - TOT2;
    const int i = id & 7, l = (id >> 3) & 63, kt = id >> 9;
    const int g = l >> 4, c = l & 15;
    const int k = kt * 32 + g * 8 + i;        // 0..319
    g_w3[id] = (_Float16)((c < 8) ? W3[k * 8 + c] : 0.f);
  }
}

// ---------------- main recurrent kernel ----------------
__global__
__attribute__((amdgpu_flat_work_group_size(NTHR, NTHR)))
__attribute__((amdgpu_waves_per_eu(4, 4)))
void knet_kernel(
    const float* __restrict__ y,    // [T,B,2]
    const float* __restrict__ Fm,   // [4,4]
    const float* __restrict__ Hm,   // [2,4]
    const float* __restrict__ bg,   // [2,600]
    const float* __restrict__ b3,   // [8]
    const float* __restrict__ hn0,  // [B,200]
    float* __restrict__ out)        // [T,B,4]
{
  // A-fragments of x_cat = [a1(480) | h(200) | 1.0 @680 | 0-pad]; a2 reuses
  // slots 0..9 between phase E and phase F.
  __shared__ alignas(16) _Float16 sAhi[KTG * 2 * 512];   // 45056 B
  __shared__ alignas(16) _Float16 sAlo[KTG * 2 * 512];   // 45056 B
  __shared__ alignas(16) float s_in8T[8][BR];
  __shared__ alignas(16) float s_kgp[2][BR][8];          // KG k-half partials
  __shared__ alignas(16) float s_bias[4][HID];
  __shared__ alignas(16) float s_fh[32];                 // Fm[16], Hm[8]
  __shared__ alignas(16) float s_b3[8];
  // r8: persistent per-row filter state, double-buffered by t-parity.
  // read idx p=t&1, write p^1; reuse is always barrier-separated.
  __shared__ alignas(16) float s_prior2[2][BR][4];
  __shared__ alignas(16) float s_d2[2][BR][2];

  const int tid  = threadIdx.x;
  const int lane = tid & 63;
  const int wid  = __builtin_amdgcn_readfirstlane(tid >> 6);  // 0..15
  const int row0 = blockIdx.x * BR;
  const int rl   = lane & 31;
  const int g4   = (lane >> 4) << 2;

  // ---- init ----
  if (tid < HID) {
    s_bias[0][tid] = bg[tid]       + bg[600 + tid];   // z
    s_bias[1][tid] = bg[200 + tid] + bg[800 + tid];   // r
    s_bias[2][tid] = bg[400 + tid];                   // xh (input bias)
    s_bias[3][tid] = bg[1000 + tid];                  // hh (recurrent bias)
  }
  if (tid < 16) s_fh[tid] = Fm[tid];
  else if (tid < 24) s_fh[tid] = Hm[tid - 16];
  if (tid < 8) s_b3[tid] = b3[tid];
  if (tid < BR * 4) {                    // zero parity-0 state (t=0 reads it)
    s_prior2[0][tid >> 2][tid & 3] = 0.f;
    if ((tid & 3) < 2) s_d2[0][tid >> 2][tid & 1] = 0.f;
  }
  for (int e = tid; e < HID * BR; e += NTHR) {
    const int j = e >> 5, r = e & 31;
    const float h0 = hn0[(size_t)(row0 + r) * HID + j];
    const int off = afrag_off(480 + j, r);
    const _Float16 hi = (_Float16)h0;
    sAhi[off] = hi;
    sAlo[off] = (_Float16)(h0 - (float)hi);
  }
  for (int e = tid; e < 24 * BR; e += NTHR) {   // k 680..703: 1.0 then zeros
    const int k = 680 + (e >> 5), r = e & 31;
    const int off = afrag_off(k, r);
    sAhi[off] = (_Float16)((k == 680) ? 1.f : 0.f);
    sAlo[off] = (_Float16)0.f;
  }
  __syncthreads();

  for (int t = 0; t < T_STEPS; ++t) {
    const int p = t & 1;
    // ================= phase 1: F2(t-1) + A(t) + W1-GEMM(t) =================
    {
      float post[4] = {0.f, 0.f, 0.f, 0.f};
      if (t > 0) {
        float kg[8];
#pragma unroll
        for (int cc = 0; cc < 8; ++cc)
          kg[cc] = s_kgp[0][rl][cc] + s_kgp[1][rl][cc] + s_b3[cc];
        const float pd0 = s_d2[p][rl][0], pd1 = s_d2[p][rl][1];
#pragma unroll
        for (int m = 0; m < 4; ++m)
          post[m] = s_prior2[p][rl][m] + kg[2 * m] * pd0 + kg[2 * m + 1] * pd1;
        if (wid == 0 && lane < 32) {
          float4 o; o.x = post[0]; o.y = post[1]; o.z = post[2]; o.w = post[3];
          *(float4*)&out[((size_t)(t - 1) * BATCH + row0 + rl) * 4] = o;
        }
      }
      // ---- A: prior / innovation / features (redundant per wave) ----
      float opri[4], np[4];
#pragma unroll
      for (int m = 0; m < 4; ++m) opri[m] = s_prior2[p][rl][m];
#pragma unroll
      for (int m = 0; m < 4; ++m) {
        float s = 0.f;
#pragma unroll
        for (int j = 0; j < 4; ++j) s += s_fh[m * 4 + j] * post[j];
        np[m] = s;
      }
      float m0 = 0.f, m1 = 0.f;
#pragma unroll
      for (int m = 0; m < 4; ++m) { m0 += s_fh[16 + m] * np[m]; m1 += s_fh[20 + m] * np[m]; }
      const float2 yv = *(const float2*)&y[((size_t)t * BATCH + row0 + rl) * 2];
      const float d0 = yv.x - m0;
      const float d1 = yv.y - m1;
      float dx[4], ssx = 0.f;
#pragma unroll
      for (int m = 0; m < 4; ++m) { dx[m] = post[m] - opri[m]; ssx += dx[m] * dx[m]; }
      const float idx_ = rsqrtf(fmaxf(ssx, 1e-12f));
      const float idy_ = rsqrtf(fmaxf(d0 * d0 + d1 * d1, 1e-12f));
      if (lane < 32) {   // identical values from all waves: benign
#pragma unroll
        for (int m = 0; m < 4; ++m) s_prior2[p ^ 1][rl][m] = np[m];
        s_d2[p ^ 1][rl][0] = d0;
        s_d2[p ^ 1][rl][1] = d1;
        const float n0 = d0 * idy_, n1 = d1 * idy_;
        s_in8T[0][rl] = n0; s_in8T[1][rl] = n1;
        s_in8T[2][rl] = n0; s_in8T[3][rl] = n1;
#pragma unroll
        for (int m = 0; m < 4; ++m) s_in8T[4 + m][rl] = dx[m] * idx_;
      }
    }
    {   // ---- W1-GEMM: a1 = relu([in8,1] @ [W1;b1]), 2 tiles/wave ----
      f16x8 ah0 = f16x8_zero(), al0 = f16x8_zero();
      f16x8 ah1 = f16x8_zero(), al1 = f16x8_zero();
      const int g = lane >> 4, c = lane & 15;
      if (g == 0) {
#pragma unroll
        for (int i = 0; i < 8; ++i) {
          const float v0 = s_in8T[i][c];
          const float v1 = s_in8T[i][c + 16];
          const _Float16 h0 = (_Float16)v0; ah0[i] = h0; al0[i] = (_Float16)(v0 - (float)h0);
          const _Float16 h1 = (_Float16)v1; ah1[i] = h1; al1[i] = (_Float16)(v1 - (float)h1);
        }
      } else if (g == 1) {
        ah0[0] = (_Float16)1.f;   // ones-row k=8 -> b1
        ah1[0] = (_Float16)1.f;
      }
      f32x4 p00 = {0.f, 0.f, 0.f, 0.f}, p01 = p00, p10 = p00, p11 = p00;
      const f16x8 w1a = *(const f16x8*)&g_w1[(size_t)wid * 512 + lane * 8];
      const f16x8 w1b = *(const f16x8*)&g_w1[(size_t)(16 + wid) * 512 + lane * 8];
      p00 = MFMA16(ah0, w1a, p00); p00 = MFMA16(al0, w1a, p00);
      p01 = MFMA16(ah1, w1a, p01); p01 = MFMA16(al1, w1a, p01);
      p10 = MFMA16(ah0, w1b, p10); p10 = MFMA16(al0, w1b, p10);
      p11 = MFMA16(ah1, w1b, p11); p11 = MFMA16(al1, w1b, p11);
#define ASTORE(A0, A1, COLBASE)                                      \
      { const int col = (COLBASE) + (lane & 15);                     \
        _Pragma("unroll")                                            \
        for (int reg = 0; reg < 4; ++reg) {                          \
          const float v0 = fmaxf(A0[reg], 0.f);                      \
          const float v1 = fmaxf(A1[reg], 0.f);                      \
          const int o0 = afrag_off(col, g4 + reg);                   \
          const int o1 = afrag_off(col, 16 + g4 + reg);              \
          const _Float16 q0 = (_Float16)v0, q1 = (_Float16)v1;       \
          sAhi[o0] = q0; sAlo[o0] = (_Float16)(v0 - (float)q0);      \
          sAhi[o1] = q1; sAlo[o1] = (_Float16)(v1 - (float)q1);      \
        } }
      ASTORE(p00, p01, wid * 16)
      if (wid < 14) ASTORE(p10, p11, (16 + wid) * 16)
    }
    __syncthreads();

    // == phase C: gates GEMM (waves 0..12; A at use, B depth-1, pinned) ==
    f32x4 aZ0 = {0.f, 0.f, 0.f, 0.f}, aZ1 = aZ0, aR0 = aZ0, aR1 = aZ0;
    f32x4 aX0 = aZ0, aX1 = aZ0, aH0 = aZ0, aH1 = aZ0;
    if (wid < 13) {
      const _Float16* bzp = g_wcat + ((size_t)(0  + wid) * KTG) * 512 + lane * 8;
      const _Float16* brp = g_wcat + ((size_t)(13 + wid) * KTG) * 512 + lane * 8;
      const _Float16* bxp = g_wcat + ((size_t)(26 + wid) * KTG) * 512 + lane * 8;
      const _Float16* bhp = g_wcat + ((size_t)(39 + wid) * KTG) * 512 + lane * 8;
#define LD3(KT) (((KT) < 15) ? *(const f16x8*)(bxp + (KT) * 512) \
                             : *(const f16x8*)(bhp + (KT) * 512))
      const int ab = lane * 8;
      f16x8 bzC = *(const f16x8*)(bzp);
      f16x8 brC = *(const f16x8*)(brp);
      f16x8 bxC = LD3(0);
#pragma unroll
      for (int kt = 0; kt < KTG; ++kt) {
        // A(kt) LDS reads at use
        const int _o = kt * 1024 + ab;
        const f16x8 cah0 = *(const f16x8*)&sAhi[_o];
        const f16x8 cal0 = *(const f16x8*)&sAlo[_o];
        const f16x8 cah1 = *(const f16x8*)&sAhi[_o + 512];
        const f16x8 cal1 = *(const f16x8*)&sAlo[_o + 512];
        // B(kt+1) global loads, issued before kt's MFMA cluster
        f16x8 bzN, brN, bxN;
        if (kt + 1 < KTG) {
          bzN = *(const f16x8*)(bzp + (kt + 1) * 512);
          brN = *(const f16x8*)(brp + (kt + 1) * 512);
          bxN = LD3(kt + 1);
        }
        SBAR();                         // pin: loads issue BEFORE kt's MFMAs
        aZ0 = MFMA16(cah0, bzC, aZ0);  aZ0 = MFMA16(cal0, bzC, aZ0);
        aZ1 = MFMA16(cah1, bzC, aZ1);  aZ1 = MFMA16(cal1, bzC, aZ1);
        aR0 = MFMA16(cah0, brC, aR0);  aR0 = MFMA16(cal0, brC, aR0);
        aR1 = MFMA16(cah1, brC, aR1);  aR1 = MFMA16(cal1, brC, aR1);
        if (kt < 15) {
          aX0 = MFMA16(cah0, bxC, aX0); aX0 = MFMA16(cal0, bxC, aX0);
          aX1 = MFMA16(cah1, bxC, aX1); aX1 = MFMA16(cal1, bxC, aX1);
        } else {
          aH0 = MFMA16(cah0, bxC, aH0); aH0 = MFMA16(cal0, bxC, aH0);
          aH1 = MFMA16(cah1, bxC, aH1); aH1 = MFMA16(cal1, bxC, aH1);
        }
        if (kt + 1 < KTG) { bzC = bzN; brC = brN; bxC = bxN; }
      }
#undef LD3
    }
    __syncthreads();   // all h reads done before in-place h update

    // ================= phase D': in-register GRU update =================
    if (wid < 13) {
      const int c = lane & 15;
      const int j = wid * 16 + c;
      if (j < HID) {
        const float bz  = s_bias[0][j], brb = s_bias[1][j];
        const float bxh = s_bias[2][j], bhh = s_bias[3][j];
#define GRU1(AZ, AR, AX, AH, MB)                                         \
        _Pragma("unroll")                                                \
        for (int reg = 0; reg < 4; ++reg) {                              \
          const int r = (MB) * 16 + g4 + reg;                            \
          const int off = afrag_off(480 + j, r);                         \
          const float hold = (float)sAhi[off] + (float)sAlo[off];        \
          const float z  = sigmoid_(AZ[reg] + bz);                       \
          const float rr = sigmoid_(AR[reg] + brb);                      \
          const float hc = tanh_((AX[reg] + bxh) + rr * (AH[reg] + bhh));\
          const float hn = z * hold + (1.f - z) * hc;                    \
          const _Float16 qh = (_Float16)hn;                              \
          sAhi[off] = qh;                                                \
          sAlo[off] = (_Float16)(hn - (float)qh);                       \
        }
        GRU1(aZ0, aR0, aX0, aH0, 0)
        GRU1(aZ1, aR1, aX1, aH1, 1)
#undef GRU1
      }
    }
    __syncthreads();

    // == phase E: a2 = relu(h @ W2 + b2); A at use, B depth-1, pinned ==
    {
      f32x4 e00 = {0.f, 0.f, 0.f, 0.f}, e01 = e00, e10 = e00, e11 = e00;
      const _Float16* w2a = g_w2 + ((size_t)wid * KT2) * 512 + lane * 8;
      const _Float16* w2b = g_w2 + ((size_t)(16 + wid) * KT2) * 512 + lane * 8;
      const int ab = lane * 8;
      f16x8 baC = *(const f16x8*)(w2a);
      f16x8 bbC = (wid < 4) ? *(const f16x8*)(w2b) : f16x8_zero();
#pragma unroll
      for (int qt = 0; qt < KT2; ++qt) {
        const int _o = (15 + qt) * 1024 + ab;
        const f16x8 cah0 = *(const f16x8*)&sAhi[_o];
        const f16x8 cal0 = *(const f16x8*)&sAlo[_o];
        const f16x8 cah1 = *(const f16x8*)&sAhi[_o + 512];
        const f16x8 cal1 = *(const f16x8*)&sAlo[_o + 512];
        f16x8 baN, bbN;
        if (qt + 1 < KT2) {
          baN = *(const f16x8*)(w2a + (qt + 1) * 512);
          if (wid < 4) bbN = *(const f16x8*)(w2b + (qt + 1) * 512);
        }
        SBAR();
        e00 = MFMA16(cah0, baC, e00); e00 = MFMA16(cal0, baC, e00);
        e01 = MFMA16(cah1, baC, e01); e01 = MFMA16(cal1, baC, e01);
        if (wid < 4) {
          e10 = MFMA16(cah0, bbC, e10); e10 = MFMA16(cal0, bbC, e10);
          e11 = MFMA16(cah1, bbC, e11); e11 = MFMA16(cal1, bbC, e11);
        }
        if (qt + 1 < KT2) { baC = baN; if (wid < 4) bbC = bbN; }
      }
      ASTORE(e00, e01, wid * 16)                       // cols < 256
      if (wid < 4) ASTORE(e10, e11, (16 + wid) * 16)   // cols 256..319
#undef ASTORE
    }
    __syncthreads();

    // ========== phase F: KG partials (4 waves, k-halves, pinned) ==========
    if (wid < 4) {
      const int mB = wid & 1, half = wid >> 1;
      f32x4 ka = {0.f, 0.f, 0.f, 0.f};
      const _Float16* w3p = g_w3 + lane * 8;
      f16x8 bwC = *(const f16x8*)(w3p + (half * 5) * 512);
#pragma unroll
      for (int q = 0; q < 5; ++q) {
        const int kt3 = half * 5 + q;
        f16x8 bwN;
        if (q + 1 < 5) bwN = *(const f16x8*)(w3p + (kt3 + 1) * 512);
        const int _o = (kt3 * 2 + mB) * 512 + lane * 8;
        const f16x8 ah = *(const f16x8*)&sAhi[_o];
        const f16x8 al = *(const f16x8*)&sAlo[_o];
        SBAR();
        ka = MFMA16(ah, bwC, ka); ka = MFMA16(al, bwC, ka);
        if (q + 1 < 5) bwC = bwN;
      }
      const int c = lane & 15;
      if (c < 8) {
        const int rb = mB * 16 + g4;
#pragma unroll
        for (int reg = 0; reg < 4; ++reg) s_kgp[half][rb + reg][c] = ka[reg];
      }
    }
    __syncthreads();
  }

  // ---- final F2 (t = T_STEPS, parity 0) ----
  {
    float kg[8];
#pragma unroll
    for (int cc = 0; cc < 8; ++cc)
      kg[cc] = s_kgp[0][rl][cc] + s_kgp[1][rl][cc] + s_b3[cc];
    const float pd0 = s_d2[0][rl][0], pd1 = s_d2[0][rl][1];
    if (wid == 0 && lane < 32) {
      float4 o;
      o.x = s_prior2[0][rl][0] + kg[0] * pd0 + kg[1] * pd1;
      o.y = s_prior2[0][rl][1] + kg[2] * pd0 + kg[3] * pd1;
      o.z = s_prior2[0][rl][2] + kg[4] * pd0 + kg[5] * pd1;
      o.w = s_prior2[0][rl][3] + kg[6] * pd0 + kg[7] * pd1;
      *(float4*)&out[((size_t)(T_STEPS - 1) * BATCH + row0 + rl) * 4] = o;
    }
  }
}

}  // namespace

extern "C" void kernel_launch(void* const* d_in, const int* in_sizes, int n_in,
                              void* d_out, int out_size, void* d_ws, size_t ws_size,
                              hipStream_t stream) {
  const float* y   = (const float*)d_in[0];
  const float* Fm  = (const float*)d_in[1];
  const float* Hm  = (const float*)d_in[2];
  const float* W1  = (const float*)d_in[3];
  const float* b1  = (const float*)d_in[4];
  const float* Wg  = (const float*)d_in[5];
  const float* Ug  = (const float*)d_in[6];
  const float* bg  = (const float*)d_in[7];
  const float* W2  = (const float*)d_in[8];
  const float* b2  = (const float*)d_in[9];
  const float* W3  = (const float*)d_in[10];
  const float* b3  = (const float*)d_in[11];
  const float* hn0 = (const float*)d_in[12];
  float* out = (float*)d_out;

  constexpr int PREP_TOT = (NTW1 + NTG * KTG + NT2 * KT2 + KT3) * 512;
  prep_kernel<<<(PREP_TOT + 255) / 256, 256, 0, stream>>>(W1, b1, Wg, Ug, W2, b2, W3);
  knet_kernel<<<BATCH / BR, NTHR, 0, stream>>>(y, Fm, Hm, bg, b3, hn0, out);
}